// Round 9
// baseline (641.372 us; speedup 1.0000x reference)
//
#include <hip/hip_runtime.h>

// ---------------------------------------------------------------------------
// GAT 3-layer classifier, bf16 intermediate storage + MFMA GEMMs.
//   CSR build -> per layer: mfma-gemm(+attn epilogue) -> aggregate -> pool/cls
// R6: single-pass softmax (no max-shift), attn fused in GEMM, log2e fold.
// R8: predicated 8-deep unrolled gather rounds.
// R9: HEAD-SLICED aggregation with XCD pinning. h stored head-major
//     (hh[head][node][64]); aggregate blocks pick head=(bx&7)>>1 so each XCD
//     (blockIdx%8 round-robin) touches only one head's 6.4MB slice ->
//     per-XCD L2 working set /4. GEMMs read/write head-major via addr tweak.
// ---------------------------------------------------------------------------

typedef __attribute__((ext_vector_type(8))) __bf16 bf16x8;
typedef __attribute__((ext_vector_type(4))) float f32x4;

#define LOG2E 1.44269504f

static __device__ __forceinline__ unsigned short f2bf(float f) {
    unsigned u = __float_as_uint(f);
    unsigned r = (u + 0x7fffu + ((u >> 16) & 1u)) >> 16;
    return (unsigned short)r;
}
static __device__ __forceinline__ float bf2f(unsigned short s) {
    return __uint_as_float(((unsigned)s) << 16);
}

// ============================ CSR build ====================================
__global__ void count_edges(const int* __restrict__ ei, int* __restrict__ deg,
                            int E, int N) {
    int i = blockIdx.x * blockDim.x + threadIdx.x;
    int tot = E + N;
    if (i >= tot) return;
    int dst = (i < E) ? ei[E + i] : (i - E);
    atomicAdd(&deg[dst], 1);
}

__global__ __launch_bounds__(256) void scan_partial(const int* __restrict__ deg,
                                                    int* __restrict__ rowptr,
                                                    int* __restrict__ blockSums, int N) {
    int t = threadIdx.x;
    int lane = t & 63, wv = t >> 6;
    int base = blockIdx.x * 1024 + t * 4;
    int v[4];
#pragma unroll
    for (int j = 0; j < 4; ++j) v[j] = (base + j < N) ? deg[base + j] : 0;
    int local = v[0] + v[1] + v[2] + v[3];
    int x = local;
#pragma unroll
    for (int off = 1; off < 64; off <<= 1) {
        int y = __shfl_up(x, off);
        if (lane >= off) x += y;
    }
    __shared__ int wsum[4];
    if (lane == 63) wsum[wv] = x;
    __syncthreads();
    int woff = 0;
    for (int i = 0; i < wv; ++i) woff += wsum[i];
    int run = woff + x - local;
#pragma unroll
    for (int j = 0; j < 4; ++j) {
        if (base + j < N) rowptr[base + j] = run;
        run += v[j];
    }
    if (t == 255) blockSums[blockIdx.x] = woff + x;
}

__global__ void scan_blocks(int* __restrict__ blockSums, int* __restrict__ rowptr,
                            int NB, int N) {
    int lane = threadIdx.x;  // 64 threads
    int carry = 0;
    for (int b0 = 0; b0 < NB; b0 += 64) {
        int i = b0 + lane;
        int v = (i < NB) ? blockSums[i] : 0;
        int x = v;
#pragma unroll
        for (int off = 1; off < 64; off <<= 1) {
            int y = __shfl_up(x, off);
            if (lane >= off) x += y;
        }
        if (i < NB) blockSums[i] = carry + x - v;
        carry += __shfl(x, 63);
    }
    if (lane == 0) rowptr[N] = carry;
}

__global__ void add_offsets(int* __restrict__ rowptr, const int* __restrict__ blockOffs,
                            int N) {
    int i = blockIdx.x * blockDim.x + threadIdx.x;
    if (i < N) rowptr[i] += blockOffs[i >> 10];
}

__global__ void scatter_edges(const int* __restrict__ ei, const int* __restrict__ rowptr,
                              int* __restrict__ fill, int* __restrict__ srcs, int E, int N) {
    int i = blockIdx.x * blockDim.x + threadIdx.x;
    int tot = E + N;
    if (i >= tot) return;
    int src, dst;
    if (i < E) { src = ei[i]; dst = ei[E + i]; }
    else       { src = i - E; dst = i - E; }
    int pos = atomicAdd(&fill[dst], 1);
    srcs[rowptr[dst] + pos] = src;
}

// ============================ casts ========================================
// Wt[n*K+k] = bf16(W[k*N+n])
__global__ void wcast(const float* __restrict__ W, unsigned short* __restrict__ Wt,
                      int K, int N) {
    int i = blockIdx.x * blockDim.x + threadIdx.x;
    if (i >= N * K) return;
    int n = i / K, k = i - n * K;
    Wt[i] = f2bf(W[(size_t)k * N + n]);
}

// ============================ MFMA GEMM + attn epilogue ====================
// C = A @ Bt^T.  AF32: A is f32 (fused cast).  AHM: A is head-major bf16
// (slice s=k/64: addr ((s*M)+row)*64 + k%64).  CHM: C written head-major.
// 128x128 tile, BK=32, 4 waves, 64x64/wave. as/ad pre-scaled by log2(e).
#define BM 128
#define BN 128
#define BK 32
#define LDK 40  // padded row stride (elements); 80B, 16B-aligned

template <bool AF32, bool AHM, bool CHM>
__global__ __launch_bounds__(256) void gemm_bf16(const void* __restrict__ Av,
                                                 const unsigned short* __restrict__ Bt,
                                                 unsigned short* __restrict__ C,
                                                 const float* __restrict__ a_src,
                                                 const float* __restrict__ a_dst,
                                                 float* __restrict__ as_o,
                                                 float* __restrict__ ad_o,
                                                 int M, int N, int K, int H) {
    __shared__ unsigned short As[BM * LDK];
    __shared__ unsigned short Bs[BN * LDK];
    int t = threadIdx.x;
    int bm = blockIdx.y * BM, bn = blockIdx.x * BN;
    int wave = t >> 6, lane = t & 63;
    int wm = (wave >> 1) * 64, wn = (wave & 1) * 64;
    int quad = lane >> 4, mr = lane & 15;

    f32x4 zero = {0.f, 0.f, 0.f, 0.f};
    f32x4 acc[4][4];
#pragma unroll
    for (int i = 0; i < 4; ++i)
#pragma unroll
        for (int j = 0; j < 4; ++j) acc[i][j] = zero;

    for (int k0 = 0; k0 < K; k0 += BK) {
        ushort4 ua[2][2];   // staged A (bf16), 2 segs x 8 elems
        float4 vb[2];
#pragma unroll
        for (int h = 0; h < 2; ++h) {
            int s = t + h * 256;
            int row = s >> 2, seg = (s & 3) * 8;
            int gra = bm + row;
            if (AF32) {
                const float* Af = (const float*)Av;
                float4 lo = make_float4(0.f, 0.f, 0.f, 0.f), hi = lo;
                if (gra < M) {
                    lo = *(const float4*)&Af[(size_t)gra * K + k0 + seg];
                    hi = *(const float4*)&Af[(size_t)gra * K + k0 + seg + 4];
                }
                ua[h][0] = make_ushort4(f2bf(lo.x), f2bf(lo.y), f2bf(lo.z), f2bf(lo.w));
                ua[h][1] = make_ushort4(f2bf(hi.x), f2bf(hi.y), f2bf(hi.z), f2bf(hi.w));
            } else {
                const unsigned short* Ab = (const unsigned short*)Av;
                float4 va = make_float4(0.f, 0.f, 0.f, 0.f);
                if (gra < M) {
                    size_t addr;
                    if (AHM) {
                        int kk = k0 + seg;
                        addr = ((size_t)(kk >> 6) * M + gra) * 64 + (kk & 63);
                    } else {
                        addr = (size_t)gra * K + k0 + seg;
                    }
                    va = *(const float4*)&Ab[addr];
                }
                ua[h][0] = *(ushort4*)&va.x;
                ua[h][1] = *(ushort4*)&va.z;
            }
            int grb = bn + row;
            vb[h] = make_float4(0.f, 0.f, 0.f, 0.f);
            if (grb < N) vb[h] = *(const float4*)&Bt[(size_t)grb * K + k0 + seg];
        }
        __syncthreads();
#pragma unroll
        for (int h = 0; h < 2; ++h) {
            int s = t + h * 256;
            int row = s >> 2, seg = (s & 3) * 8;
            *(ushort4*)&As[row * LDK + seg]     = ua[h][0];
            *(ushort4*)&As[row * LDK + seg + 4] = ua[h][1];
            *(float4*)&Bs[row * LDK + seg] = vb[h];
        }
        __syncthreads();

        bf16x8 af[4], bfr[4];
#pragma unroll
        for (int i = 0; i < 4; ++i) {
            af[i]  = *(bf16x8*)&As[(wm + i * 16 + mr) * LDK + quad * 8];
            bfr[i] = *(bf16x8*)&Bs[(wn + i * 16 + mr) * LDK + quad * 8];
        }
#pragma unroll
        for (int i = 0; i < 4; ++i)
#pragma unroll
            for (int j = 0; j < 4; ++j)
                acc[i][j] = __builtin_amdgcn_mfma_f32_16x16x32_bf16(af[i], bfr[j], acc[i][j], 0, 0, 0);
    }

    // attn coefficients: this wave's 64 cols == head (bn+wn)/64
    int colbase = bn + wn;
    if (colbase + 64 <= N) {
        int head = colbase >> 6;
        float asv[4], adv[4];
#pragma unroll
        for (int j = 0; j < 4; ++j) {
            asv[j] = a_src[head * 64 + j * 16 + mr];
            adv[j] = a_dst[head * 64 + j * 16 + mr];
        }
#pragma unroll
        for (int i = 0; i < 4; ++i) {
#pragma unroll
            for (int r = 0; r < 4; ++r) {
                float ps = acc[i][0][r] * asv[0] + acc[i][1][r] * asv[1]
                         + acc[i][2][r] * asv[2] + acc[i][3][r] * asv[3];
                float pd = acc[i][0][r] * adv[0] + acc[i][1][r] * adv[1]
                         + acc[i][2][r] * adv[2] + acc[i][3][r] * adv[3];
#pragma unroll
                for (int off2 = 1; off2 < 16; off2 <<= 1) {
                    ps += __shfl_xor(ps, off2);
                    pd += __shfl_xor(pd, off2);
                }
                int grow = bm + wm + i * 16 + quad * 4 + r;
                if (mr == 0 && grow < M) {
                    as_o[(size_t)grow * H + head] = ps * LOG2E;
                    ad_o[(size_t)grow * H + head] = pd * LOG2E;
                }
            }
        }
    }

    // C store: C/D layout col=lane&15, row=quad*4+reg
    int headc = (bn + wn) >> 6;
#pragma unroll
    for (int i = 0; i < 4; ++i) {
#pragma unroll
        for (int r = 0; r < 4; ++r) {
            int grow = bm + wm + i * 16 + quad * 4 + r;
            if (grow >= M) continue;
#pragma unroll
            for (int j = 0; j < 4; ++j) {
                int gcol = bn + wn + j * 16 + mr;
                if (gcol < N) {
                    if (CHM) {
                        C[((size_t)headc * M + grow) * 64 + (j * 16 + mr)] = f2bf(acc[i][j][r]);
                    } else {
                        C[(size_t)grow * N + gcol] = f2bf(acc[i][j][r]);
                    }
                }
            }
        }
    }
}

// ============================ head-sliced aggregation ======================
// Single-pass unnormalized softmax, one wave per (node, head), 64 lanes =
// 64 channels (2B gathers from the head-major slice). head = (bx&7)>>1 pins
// each head to one XCD pair (blockIdx%8 round-robin): per-XCD h working set
// = 6.4MB instead of 26MB. Predicated 8-deep unroll (R8 structure).
template <int H>
__global__ __launch_bounds__(256) void gat_aggregate_hm(const unsigned short* __restrict__ hh,
                                                        const float* __restrict__ as_i,
                                                        const float* __restrict__ ad_i,
                                                        const int* __restrict__ rowptr,
                                                        const int* __restrict__ srcs,
                                                        const float* __restrict__ bias,
                                                        unsigned short* __restrict__ out_hm,
                                                        int N) {
    int bx = blockIdx.x;
    int head = (bx & 7) >> 1;
    int sub = bx & 1;
    int g = bx >> 3;
    int P = (N + 3) >> 2;          // node-blocks per head
    int nb = g * 2 + sub;
    if (nb >= P) return;
    int wv = threadIdx.x >> 6, lane = threadIdx.x & 63;
    int node = nb * 4 + wv;
    if (node >= N) return;

    int row = rowptr[node], end = rowptr[node + 1];
    int len = end - row;
    float advh = ad_i[(size_t)node * H + head];
    const unsigned short* hbase = hh + (size_t)head * N * 64;

    float acc = 0.f, l = 0.f;
    const int U = 8;
    for (int base = 0; base < len; base += U) {
        int s[U];
        float cf[U];
#pragma unroll
        for (int u = 0; u < U; ++u) {
            int idx = base + u;
            int ii = row + ((idx < len) ? idx : (len - 1));
            s[u] = srcs[ii];
        }
#pragma unroll
        for (int u = 0; u < U; ++u) cf[u] = as_i[(size_t)s[u] * H + head];
        unsigned short r[U];
#pragma unroll
        for (int u = 0; u < U; ++u) r[u] = hbase[(size_t)s[u] * 64 + lane];
#pragma unroll
        for (int u = 0; u < U; ++u) {
            float e = cf[u] + advh;
            e = (e > 0.f) ? e : 0.2f * e;
            float wgt = (base + u < len) ? exp2f(e) : 0.f;
            l += wgt;
            acc += wgt * bf2f(r[u]);
        }
    }

    float v = acc / (l + 1e-16f) + bias[head * 64 + lane];
    v = (v > 0.f) ? v : (__expf(v) - 1.f);
    out_hm[((size_t)head * N + node) * 64 + lane] = f2bf(v);
}

// ============================ layer-3 aggregation (H=1) ====================
template <int H, int VPL, bool OUTF32>
__global__ __launch_bounds__(256) void gat_aggregate(const unsigned short* __restrict__ hbuf,
                                                     const float* __restrict__ as_i,
                                                     const float* __restrict__ ad_i,
                                                     const int* __restrict__ rowptr,
                                                     const int* __restrict__ srcs,
                                                     const float* __restrict__ bias,
                                                     void* __restrict__ out_v, int N) {
    const int HC = 64 * VPL;
    int node = (blockIdx.x * blockDim.x + threadIdx.x) >> 6;
    int lane = threadIdx.x & 63;
    if (node >= N) return;
    int row = rowptr[node], end = rowptr[node + 1];
    int len = end - row;
    const int hd_lane = (lane * VPL) >> 6;

    float advh = ad_i[(size_t)node * H + hd_lane];

    float acc[VPL];
#pragma unroll
    for (int j = 0; j < VPL; ++j) acc[j] = 0.f;
    float l = 0.f;

    const int U = 8;
    for (int base = 0; base < len; base += U) {
        int s[U];
        float cf[U];
#pragma unroll
        for (int u = 0; u < U; ++u) {
            int idx = base + u;
            int ii = row + ((idx < len) ? idx : (len - 1));
            s[u] = srcs[ii];
        }
#pragma unroll
        for (int u = 0; u < U; ++u) cf[u] = as_i[(size_t)s[u] * H + hd_lane];
        unsigned short r[U];
#pragma unroll
        for (int u = 0; u < U; ++u) r[u] = hbuf[(size_t)s[u] * HC + lane];
#pragma unroll
        for (int u = 0; u < U; ++u) {
            float e = cf[u] + advh;
            e = (e > 0.f) ? e : 0.2f * e;
            float wgt = (base + u < len) ? exp2f(e) : 0.f;
            l += wgt;
            acc[0] += wgt * bf2f(r[u]);
        }
    }

    float inv_l = 1.f / (l + 1e-16f);
    float v = acc[0] * inv_l + bias[lane];
    v = (v > 0.f) ? v : (__expf(v) - 1.f);
    if (OUTF32) {
        ((float*)out_v)[(size_t)node * HC + lane] = v;
    } else {
        ((unsigned short*)out_v)[(size_t)node * HC + lane] = f2bf(v);
    }
}

// ============================ pool + classify ==============================
#define POOL_CHUNK 128
__global__ __launch_bounds__(256) void pool_kernel(const float* __restrict__ hf,
                                                   const int* __restrict__ batch,
                                                   float* __restrict__ sums,
                                                   float* __restrict__ counts, int N) {
    int t = threadIdx.x;
    int c = t & 63, sub = t >> 6;
    int start = blockIdx.x * POOL_CHUNK;
    int end = min(start + POOL_CHUNK, N);
    float acc = 0.f, cnt = 0.f;
    int cur = -1;
    for (int n = start + sub; n < end; n += 4) {
        int g = batch[n];
        if (g != cur) {
            if (cur >= 0) {
                atomicAdd(&sums[cur * 64 + c], acc);
                if (c == 0) atomicAdd(&counts[cur], cnt);
            }
            cur = g; acc = 0.f; cnt = 0.f;
        }
        acc += hf[(size_t)n * 64 + c];
        cnt += 1.f;
    }
    if (cur >= 0) {
        atomicAdd(&sums[cur * 64 + c], acc);
        if (c == 0) atomicAdd(&counts[cur], cnt);
    }
}

__global__ void classify(const float* __restrict__ sums, const float* __restrict__ counts,
                         const float* __restrict__ Wc, const float* __restrict__ bc,
                         float* __restrict__ out, int NC) {
    __shared__ float p[64];
    int g = blockIdx.x;
    if (threadIdx.x < 64) {
        float cnt = fmaxf(counts[g], 1.0f);
        p[threadIdx.x] = sums[g * 64 + threadIdx.x] / cnt;
    }
    __syncthreads();
    int k = threadIdx.x;
    if (k < NC) {
        float acc = bc[k];
        for (int c = 0; c < 64; ++c) acc += p[c] * Wc[c * NC + k];
        out[g * NC + k] = acc;
    }
}

static inline size_t align_up(size_t x, size_t a) { return (x + a - 1) / a * a; }

extern "C" void kernel_launch(void* const* d_in, const int* in_sizes, int n_in,
                              void* d_out, int out_size, void* d_ws, size_t ws_size,
                              hipStream_t stream) {
    const float* x      = (const float*)d_in[0];
    const int*   ei     = (const int*)d_in[1];
    const int*   batch  = (const int*)d_in[2];
    const float* W1     = (const float*)d_in[3];
    const float* a_src1 = (const float*)d_in[4];
    const float* a_dst1 = (const float*)d_in[5];
    const float* b1     = (const float*)d_in[6];
    const float* W2     = (const float*)d_in[7];
    const float* a_src2 = (const float*)d_in[8];
    const float* a_dst2 = (const float*)d_in[9];
    const float* b2     = (const float*)d_in[10];
    const float* W3     = (const float*)d_in[11];
    const float* a_src3 = (const float*)d_in[12];
    const float* a_dst3 = (const float*)d_in[13];
    const float* b3     = (const float*)d_in[14];
    const float* Wc     = (const float*)d_in[15];
    const float* bc     = (const float*)d_in[16];

    const int N    = in_sizes[2];
    const int E    = in_sizes[1] / 2;
    const int F_IN = in_sizes[0] / N;   // 128
    const int HC   = in_sizes[6];       // 256
    const int C    = in_sizes[14];      // 64
    const int NC   = in_sizes[16];      // 200
    const int Etot = E + N;
    const int NB   = (N + 1023) / 1024;
    const int NPB  = (N + POOL_CHUNK - 1) / POOL_CHUNK;

    char* w = (char*)d_ws;
    size_t off = 0;
    auto alloc = [&](size_t bytes) -> void* {
        void* p = w + off;
        off = align_up(off + bytes, 256);
        return p;
    };
    int*   deg    = (int*)alloc((size_t)N * 4);
    int*   fill   = (int*)alloc((size_t)N * 4);   // adjacent to deg: one memset
    int*   rowptr = (int*)alloc((size_t)(N + 1) * 4);
    int*   srcs   = (int*)alloc((size_t)Etot * 4);
    int*   bsums  = (int*)alloc((size_t)NB * 4);
    float* as_buf = (float*)alloc((size_t)N * 4 * 4);
    float* ad_buf = (float*)alloc((size_t)N * 4 * 4);
    unsigned short* Wt1 = (unsigned short*)alloc((size_t)HC * F_IN * 2);
    unsigned short* Wt2 = (unsigned short*)alloc((size_t)HC * HC * 2);
    unsigned short* Wt3 = (unsigned short*)alloc((size_t)C * HC * 2);
    unsigned short* hA  = (unsigned short*)alloc((size_t)N * HC * 2);
    unsigned short* hB  = (unsigned short*)alloc((size_t)N * HC * 2);
    unsigned short* hC  = (unsigned short*)alloc((size_t)N * C * 2);
    float* bufF   = (float*)alloc((size_t)N * C * 4);
    float* sums   = (float*)alloc((size_t)(64 * 64 + 64) * 4);
    float* counts = sums + 64 * 64;

    const int TPB = 256;

    // ---- CSR build ----
    hipMemsetAsync(deg, 0, (char*)fill - (char*)deg + (size_t)N * 4, stream);
    count_edges<<<(Etot + TPB - 1) / TPB, TPB, 0, stream>>>(ei, deg, E, N);
    scan_partial<<<NB, 256, 0, stream>>>(deg, rowptr, bsums, N);
    scan_blocks<<<1, 64, 0, stream>>>(bsums, rowptr, NB, N);
    add_offsets<<<(N + TPB - 1) / TPB, TPB, 0, stream>>>(rowptr, bsums, N);
    scatter_edges<<<(Etot + TPB - 1) / TPB, TPB, 0, stream>>>(ei, rowptr, fill, srcs, E, N);

    // ---- weight casts ----
    wcast<<<(HC * F_IN + TPB - 1) / TPB, TPB, 0, stream>>>(W1, Wt1, F_IN, HC);
    wcast<<<(HC * HC + TPB - 1) / TPB, TPB, 0, stream>>>(W2, Wt2, HC, HC);
    wcast<<<(C * HC + TPB - 1) / TPB, TPB, 0, stream>>>(W3, Wt3, HC, C);

    dim3 gWide((HC + BN - 1) / BN, (N + BM - 1) / BM);
    dim3 gNarrow((C + BN - 1) / BN, (N + BM - 1) / BM);
    int P = (N + 3) / 4;
    int aggHM = 8 * ((P + 1) / 2);      // head-sliced aggregate grid
    int waveBlocks = (N + 3) / 4;       // layer-3 aggregate

    // ---- Layer 1 (A = f32 x; C head-major) ----
    gemm_bf16<true, false, true><<<gWide, 256, 0, stream>>>(x, Wt1, hA, a_src1, a_dst1, as_buf, ad_buf, N, HC, F_IN, 4);
    gat_aggregate_hm<4><<<aggHM, 256, 0, stream>>>(hA, as_buf, ad_buf, rowptr, srcs, b1, hB, N);

    // ---- Layer 2 (A head-major; C head-major) ----
    gemm_bf16<false, true, true><<<gWide, 256, 0, stream>>>(hB, Wt2, hA, a_src2, a_dst2, as_buf, ad_buf, N, HC, HC, 4);
    gat_aggregate_hm<4><<<aggHM, 256, 0, stream>>>(hA, as_buf, ad_buf, rowptr, srcs, b2, hB, N);

    // ---- Layer 3 (H=1; A head-major; C row-major) ----
    gemm_bf16<false, true, false><<<gNarrow, 256, 0, stream>>>(hB, Wt3, hC, a_src3, a_dst3, as_buf, ad_buf, N, C, HC, 1);
    gat_aggregate<1, 1, true><<<waveBlocks, 256, 0, stream>>>(hC, as_buf, ad_buf, rowptr, srcs, b3, bufF, N);

    // ---- Pool + classify ----
    hipMemsetAsync(sums, 0, (size_t)(64 * 64 + 64) * 4, stream);
    pool_kernel<<<NPB, 256, 0, stream>>>(bufF, batch, sums, counts, N);
    classify<<<64, 256, 0, stream>>>(sums, counts, Wc, bc, (float*)d_out, NC);
}

// Round 10
// 474.662 us; speedup vs baseline: 1.3512x; 1.3512x over previous
//
#include <hip/hip_runtime.h>

// ---------------------------------------------------------------------------
// GAT 3-layer classifier, bf16 intermediate storage + MFMA GEMMs.
//   CSR build -> per layer: mfma-gemm(+attn epilogue) -> aggregate -> pool/cls
// R6: single-pass softmax (no max-shift), attn fused in GEMM, log2e fold.
// R8: aggregate = one wave/node, predicated 8-deep unrolled gather rounds.
// R9 (REVERTED): head-sliced agg cut FETCH 208->139MB but 4x'd per-edge VALU
//     (VALUBusy 104%, 71->166us). Aggregate is at its structural floor:
//     ~208MB compulsory per-XCD L2 fill @ ~3-3.5TB/s + ~74% VALU.
// R10: GEMM staging via __builtin_amdgcn_global_load_lds (16B) -- removes the
//     VGPR round-trip (guide m93->m97 = 1.69x). LDS pad replaced by XOR
//     swizzle seg^=(row>>1)&3 (DMA needs contiguous lane*16 dst; swizzled
//     ds_read_b128 is 2-way-aliased = free). GEMM-1 A pre-cast by xcast.
// ---------------------------------------------------------------------------

typedef __attribute__((ext_vector_type(8))) __bf16 bf16x8;
typedef __attribute__((ext_vector_type(4))) float f32x4;

#define LOG2E 1.44269504f

static __device__ __forceinline__ unsigned short f2bf(float f) {
    unsigned u = __float_as_uint(f);
    unsigned r = (u + 0x7fffu + ((u >> 16) & 1u)) >> 16;
    return (unsigned short)r;
}
static __device__ __forceinline__ float bf2f(unsigned short s) {
    return __uint_as_float(((unsigned)s) << 16);
}

static __device__ __forceinline__ void g2lds16(const unsigned short* g,
                                               unsigned short* l) {
    __builtin_amdgcn_global_load_lds(
        (const __attribute__((address_space(1))) unsigned int*)g,
        (__attribute__((address_space(3))) unsigned int*)l, 16, 0, 0);
}

// ============================ CSR build ====================================
__global__ void count_edges(const int* __restrict__ ei, int* __restrict__ deg,
                            int E, int N) {
    int i = blockIdx.x * blockDim.x + threadIdx.x;
    int tot = E + N;
    if (i >= tot) return;
    int dst = (i < E) ? ei[E + i] : (i - E);
    atomicAdd(&deg[dst], 1);
}

__global__ __launch_bounds__(256) void scan_partial(const int* __restrict__ deg,
                                                    int* __restrict__ rowptr,
                                                    int* __restrict__ blockSums, int N) {
    int t = threadIdx.x;
    int lane = t & 63, wv = t >> 6;
    int base = blockIdx.x * 1024 + t * 4;
    int v[4];
#pragma unroll
    for (int j = 0; j < 4; ++j) v[j] = (base + j < N) ? deg[base + j] : 0;
    int local = v[0] + v[1] + v[2] + v[3];
    int x = local;
#pragma unroll
    for (int off = 1; off < 64; off <<= 1) {
        int y = __shfl_up(x, off);
        if (lane >= off) x += y;
    }
    __shared__ int wsum[4];
    if (lane == 63) wsum[wv] = x;
    __syncthreads();
    int woff = 0;
    for (int i = 0; i < wv; ++i) woff += wsum[i];
    int run = woff + x - local;
#pragma unroll
    for (int j = 0; j < 4; ++j) {
        if (base + j < N) rowptr[base + j] = run;
        run += v[j];
    }
    if (t == 255) blockSums[blockIdx.x] = woff + x;
}

__global__ void scan_blocks(int* __restrict__ blockSums, int* __restrict__ rowptr,
                            int NB, int N) {
    int lane = threadIdx.x;  // 64 threads
    int carry = 0;
    for (int b0 = 0; b0 < NB; b0 += 64) {
        int i = b0 + lane;
        int v = (i < NB) ? blockSums[i] : 0;
        int x = v;
#pragma unroll
        for (int off = 1; off < 64; off <<= 1) {
            int y = __shfl_up(x, off);
            if (lane >= off) x += y;
        }
        if (i < NB) blockSums[i] = carry + x - v;
        carry += __shfl(x, 63);
    }
    if (lane == 0) rowptr[N] = carry;
}

__global__ void add_offsets(int* __restrict__ rowptr, const int* __restrict__ blockOffs,
                            int N) {
    int i = blockIdx.x * blockDim.x + threadIdx.x;
    if (i < N) rowptr[i] += blockOffs[i >> 10];
}

__global__ void scatter_edges(const int* __restrict__ ei, const int* __restrict__ rowptr,
                              int* __restrict__ fill, int* __restrict__ srcs, int E, int N) {
    int i = blockIdx.x * blockDim.x + threadIdx.x;
    int tot = E + N;
    if (i >= tot) return;
    int src, dst;
    if (i < E) { src = ei[i]; dst = ei[E + i]; }
    else       { src = i - E; dst = i - E; }
    int pos = atomicAdd(&fill[dst], 1);
    srcs[rowptr[dst] + pos] = src;
}

// ============================ casts ========================================
__global__ void xcast(const float* __restrict__ x, unsigned short* __restrict__ xb,
                      int total4) {
    int i = blockIdx.x * blockDim.x + threadIdx.x;
    if (i >= total4) return;
    float4 v = ((const float4*)x)[i];
    ushort4 o;
    o.x = f2bf(v.x); o.y = f2bf(v.y); o.z = f2bf(v.z); o.w = f2bf(v.w);
    ((ushort4*)xb)[i] = o;
}

// Wt[n*K+k] = bf16(W[k*N+n])
__global__ void wcast(const float* __restrict__ W, unsigned short* __restrict__ Wt,
                      int K, int N) {
    int i = blockIdx.x * blockDim.x + threadIdx.x;
    if (i >= N * K) return;
    int n = i / K, k = i - n * K;
    Wt[i] = f2bf(W[(size_t)k * N + n]);
}

// ============================ MFMA GEMM + attn epilogue ====================
// C[M,N](bf16) = A[M,K](bf16) @ Bt[N,K](bf16)^T.  128x128 tile, BK=32,
// 4 waves, 64x64/wave.  Staging via global_load_lds width=16: thread t,
// iter h covers LDS slot s=(wave*2+h)*64+lane; row=s>>2; the 16B segment
// stored at LDS (row, s&3) is global (row, (s&3)^((row>>1)&3)) -- XOR
// swizzle makes fragment ds_read_b128 2-way bank-aliased (free).
// Epilogue: wave's 64-col span == one head; as/ad pre-scaled by log2(e).
#define BM 128
#define BN 128
#define BK 32

__global__ __launch_bounds__(256) void gemm_bf16(const unsigned short* __restrict__ A,
                                                 const unsigned short* __restrict__ Bt,
                                                 unsigned short* __restrict__ C,
                                                 const float* __restrict__ a_src,
                                                 const float* __restrict__ a_dst,
                                                 float* __restrict__ as_o,
                                                 float* __restrict__ ad_o,
                                                 int M, int N, int K, int H) {
    __shared__ unsigned short As[BM * BK];
    __shared__ unsigned short Bs[BN * BK];
    int t = threadIdx.x;
    int bm = blockIdx.y * BM, bn = blockIdx.x * BN;
    int wave = t >> 6, lane = t & 63;
    int wm = (wave >> 1) * 64, wn = (wave & 1) * 64;
    int quad = lane >> 4, mr = lane & 15;

    f32x4 zero = {0.f, 0.f, 0.f, 0.f};
    f32x4 acc[4][4];
#pragma unroll
    for (int i = 0; i < 4; ++i)
#pragma unroll
        for (int j = 0; j < 4; ++j) acc[i][j] = zero;

    // fragment LDS element offsets (swizzled): row*32 + (quad^((row>>1)&3))*8
    int sw = quad ^ ((mr >> 1) & 3);   // (row>>1)&3 depends only on mr (wm,i*16 are mult of 8... of 16)
    int aoff[4], boff[4];
#pragma unroll
    for (int i = 0; i < 4; ++i) {
        aoff[i] = (wm + i * 16 + mr) * BK + sw * 8;
        boff[i] = (wn + i * 16 + mr) * BK + sw * 8;
    }

    for (int k0 = 0; k0 < K; k0 += BK) {
        __syncthreads();   // prior iteration's reads done before overwrite
#pragma unroll
        for (int h = 0; h < 2; ++h) {
            int slotbase = (wave * 2 + h) * 64;
            int slot = slotbase + lane;
            int row = slot >> 2;
            int sg = (slot & 3) ^ ((row >> 1) & 3);
            int gra = bm + row;
            if (gra < M)
                g2lds16(&A[(size_t)gra * K + k0 + sg * 8], &As[slotbase * 8]);
            int grb = bn + row;
            if (grb < N)
                g2lds16(&Bt[(size_t)grb * K + k0 + sg * 8], &Bs[slotbase * 8]);
        }
        __syncthreads();

        bf16x8 af[4], bfr[4];
#pragma unroll
        for (int i = 0; i < 4; ++i) {
            af[i]  = *(bf16x8*)&As[aoff[i]];
            bfr[i] = *(bf16x8*)&Bs[boff[i]];
        }
#pragma unroll
        for (int i = 0; i < 4; ++i)
#pragma unroll
            for (int j = 0; j < 4; ++j)
                acc[i][j] = __builtin_amdgcn_mfma_f32_16x16x32_bf16(af[i], bfr[j], acc[i][j], 0, 0, 0);
    }

    // attn coefficients: this wave's 64 cols == head (bn+wn)/64
    int colbase = bn + wn;
    if (colbase + 64 <= N) {
        int head = colbase >> 6;
        float asv[4], adv[4];
#pragma unroll
        for (int j = 0; j < 4; ++j) {
            asv[j] = a_src[head * 64 + j * 16 + mr];
            adv[j] = a_dst[head * 64 + j * 16 + mr];
        }
#pragma unroll
        for (int i = 0; i < 4; ++i) {
#pragma unroll
            for (int r = 0; r < 4; ++r) {
                float ps = acc[i][0][r] * asv[0] + acc[i][1][r] * asv[1]
                         + acc[i][2][r] * asv[2] + acc[i][3][r] * asv[3];
                float pd = acc[i][0][r] * adv[0] + acc[i][1][r] * adv[1]
                         + acc[i][2][r] * adv[2] + acc[i][3][r] * adv[3];
#pragma unroll
                for (int off2 = 1; off2 < 16; off2 <<= 1) {
                    ps += __shfl_xor(ps, off2);
                    pd += __shfl_xor(pd, off2);
                }
                int grow = bm + wm + i * 16 + quad * 4 + r;
                if (mr == 0 && grow < M) {
                    as_o[(size_t)grow * H + head] = ps * LOG2E;
                    ad_o[(size_t)grow * H + head] = pd * LOG2E;
                }
            }
        }
    }

    // C store: C/D layout col=lane&15, row=quad*4+reg
#pragma unroll
    for (int i = 0; i < 4; ++i) {
#pragma unroll
        for (int r = 0; r < 4; ++r) {
            int grow = bm + wm + i * 16 + quad * 4 + r;
            if (grow >= M) continue;
#pragma unroll
            for (int j = 0; j < 4; ++j) {
                int gcol = bn + wn + j * 16 + mr;
                if (gcol < N) C[(size_t)grow * N + gcol] = f2bf(acc[i][j][r]);
            }
        }
    }
}

// ============================ aggregation ==================================
// Single-pass unnormalized softmax: out = sum(exp(e)*h) / (sum(exp(e))+eps).
// as/ad pre-scaled by log2(e) -> exp2 in the hot loop.
// One wave per node; predicated 8-deep unrolled gather rounds (R8).
template <int H, int VPL, bool OUTF32>
__global__ __launch_bounds__(256) void gat_aggregate(const unsigned short* __restrict__ hbuf,
                                                     const float* __restrict__ as_i,
                                                     const float* __restrict__ ad_i,
                                                     const int* __restrict__ rowptr,
                                                     const int* __restrict__ srcs,
                                                     const float* __restrict__ bias,
                                                     void* __restrict__ out_v, int N) {
    const int HC = 64 * VPL;
    int node = (blockIdx.x * blockDim.x + threadIdx.x) >> 6;
    int lane = threadIdx.x & 63;
    if (node >= N) return;
    int row = rowptr[node], end = rowptr[node + 1];
    int len = end - row;
    const int hd_lane = (lane * VPL) >> 6;

    float advh = ad_i[(size_t)node * H + hd_lane];

    float acc[VPL];
#pragma unroll
    for (int j = 0; j < VPL; ++j) acc[j] = 0.f;
    float l = 0.f;

    const int U = 8;
    for (int base = 0; base < len; base += U) {
        int s[U];
        float cf[U];
#pragma unroll
        for (int u = 0; u < U; ++u) {
            int idx = base + u;
            int ii = row + ((idx < len) ? idx : (len - 1));
            s[u] = srcs[ii];
        }
#pragma unroll
        for (int u = 0; u < U; ++u) cf[u] = as_i[(size_t)s[u] * H + hd_lane];
        if (VPL == 4) {
            ushort4 r[U];
#pragma unroll
            for (int u = 0; u < U; ++u)
                r[u] = *(const ushort4*)&hbuf[(size_t)s[u] * HC + lane * 4];
#pragma unroll
            for (int u = 0; u < U; ++u) {
                float e = cf[u] + advh;
                e = (e > 0.f) ? e : 0.2f * e;
                float wgt = (base + u < len) ? exp2f(e) : 0.f;
                l += wgt;
                acc[0] += wgt * bf2f(r[u].x);
                acc[1] += wgt * bf2f(r[u].y);
                acc[2] += wgt * bf2f(r[u].z);
                acc[3] += wgt * bf2f(r[u].w);
            }
        } else {
            unsigned short r[U];
#pragma unroll
            for (int u = 0; u < U; ++u) r[u] = hbuf[(size_t)s[u] * HC + lane];
#pragma unroll
            for (int u = 0; u < U; ++u) {
                float e = cf[u] + advh;
                e = (e > 0.f) ? e : 0.2f * e;
                float wgt = (base + u < len) ? exp2f(e) : 0.f;
                l += wgt;
                acc[0] += wgt * bf2f(r[u]);
            }
        }
    }

    float inv_l = 1.f / (l + 1e-16f);
    float vals[VPL];
#pragma unroll
    for (int j = 0; j < VPL; ++j) {
        float v = acc[j] * inv_l + bias[lane * VPL + j];
        vals[j] = (v > 0.f) ? v : (__expf(v) - 1.f);
    }
    if (OUTF32) {
        float* out = (float*)out_v;
#pragma unroll
        for (int j = 0; j < VPL; ++j)
            out[(size_t)node * HC + lane * VPL + j] = vals[j];
    } else {
        unsigned short* out = (unsigned short*)out_v;
        if (VPL == 4) {
            ushort4 o;
            o.x = f2bf(vals[0]); o.y = f2bf(vals[1]);
            o.z = f2bf(vals[2]); o.w = f2bf(vals[3]);
            *(ushort4*)&out[(size_t)node * HC + lane * 4] = o;
        } else {
            out[(size_t)node * HC + lane] = f2bf(vals[0]);
        }
    }
}

// ============================ pool + classify ==============================
#define POOL_CHUNK 128
__global__ __launch_bounds__(256) void pool_kernel(const float* __restrict__ hf,
                                                   const int* __restrict__ batch,
                                                   float* __restrict__ sums,
                                                   float* __restrict__ counts, int N) {
    int t = threadIdx.x;
    int c = t & 63, sub = t >> 6;
    int start = blockIdx.x * POOL_CHUNK;
    int end = min(start + POOL_CHUNK, N);
    float acc = 0.f, cnt = 0.f;
    int cur = -1;
    for (int n = start + sub; n < end; n += 4) {
        int g = batch[n];
        if (g != cur) {
            if (cur >= 0) {
                atomicAdd(&sums[cur * 64 + c], acc);
                if (c == 0) atomicAdd(&counts[cur], cnt);
            }
            cur = g; acc = 0.f; cnt = 0.f;
        }
        acc += hf[(size_t)n * 64 + c];
        cnt += 1.f;
    }
    if (cur >= 0) {
        atomicAdd(&sums[cur * 64 + c], acc);
        if (c == 0) atomicAdd(&counts[cur], cnt);
    }
}

__global__ void classify(const float* __restrict__ sums, const float* __restrict__ counts,
                         const float* __restrict__ Wc, const float* __restrict__ bc,
                         float* __restrict__ out, int NC) {
    __shared__ float p[64];
    int g = blockIdx.x;
    if (threadIdx.x < 64) {
        float cnt = fmaxf(counts[g], 1.0f);
        p[threadIdx.x] = sums[g * 64 + threadIdx.x] / cnt;
    }
    __syncthreads();
    int k = threadIdx.x;
    if (k < NC) {
        float acc = bc[k];
        for (int c = 0; c < 64; ++c) acc += p[c] * Wc[c * NC + k];
        out[g * NC + k] = acc;
    }
}

static inline size_t align_up(size_t x, size_t a) { return (x + a - 1) / a * a; }

extern "C" void kernel_launch(void* const* d_in, const int* in_sizes, int n_in,
                              void* d_out, int out_size, void* d_ws, size_t ws_size,
                              hipStream_t stream) {
    const float* x      = (const float*)d_in[0];
    const int*   ei     = (const int*)d_in[1];
    const int*   batch  = (const int*)d_in[2];
    const float* W1     = (const float*)d_in[3];
    const float* a_src1 = (const float*)d_in[4];
    const float* a_dst1 = (const float*)d_in[5];
    const float* b1     = (const float*)d_in[6];
    const float* W2     = (const float*)d_in[7];
    const float* a_src2 = (const float*)d_in[8];
    const float* a_dst2 = (const float*)d_in[9];
    const float* b2     = (const float*)d_in[10];
    const float* W3     = (const float*)d_in[11];
    const float* a_src3 = (const float*)d_in[12];
    const float* a_dst3 = (const float*)d_in[13];
    const float* b3     = (const float*)d_in[14];
    const float* Wc     = (const float*)d_in[15];
    const float* bc     = (const float*)d_in[16];

    const int N    = in_sizes[2];
    const int E    = in_sizes[1] / 2;
    const int F_IN = in_sizes[0] / N;   // 128
    const int HC   = in_sizes[6];       // 256
    const int C    = in_sizes[14];      // 64
    const int NC   = in_sizes[16];      // 200
    const int Etot = E + N;
    const int NB   = (N + 1023) / 1024;
    const int NPB  = (N + POOL_CHUNK - 1) / POOL_CHUNK;

    char* w = (char*)d_ws;
    size_t off = 0;
    auto alloc = [&](size_t bytes) -> void* {
        void* p = w + off;
        off = align_up(off + bytes, 256);
        return p;
    };
    int*   deg    = (int*)alloc((size_t)N * 4);
    int*   fill   = (int*)alloc((size_t)N * 4);   // adjacent to deg: one memset
    int*   rowptr = (int*)alloc((size_t)(N + 1) * 4);
    int*   srcs   = (int*)alloc((size_t)Etot * 4);
    int*   bsums  = (int*)alloc((size_t)NB * 4);
    float* as_buf = (float*)alloc((size_t)N * 4 * 4);
    float* ad_buf = (float*)alloc((size_t)N * 4 * 4);
    unsigned short* xb  = (unsigned short*)alloc((size_t)N * F_IN * 2);
    unsigned short* Wt1 = (unsigned short*)alloc((size_t)HC * F_IN * 2);
    unsigned short* Wt2 = (unsigned short*)alloc((size_t)HC * HC * 2);
    unsigned short* Wt3 = (unsigned short*)alloc((size_t)C * HC * 2);
    unsigned short* hA  = (unsigned short*)alloc((size_t)N * HC * 2);
    unsigned short* hB  = (unsigned short*)alloc((size_t)N * HC * 2);
    unsigned short* hC  = (unsigned short*)alloc((size_t)N * C * 2);
    float* bufF   = (float*)alloc((size_t)N * C * 4);
    float* sums   = (float*)alloc((size_t)(64 * 64 + 64) * 4);
    float* counts = sums + 64 * 64;

    const int TPB = 256;

    // ---- CSR build ----
    hipMemsetAsync(deg, 0, (char*)fill - (char*)deg + (size_t)N * 4, stream);
    count_edges<<<(Etot + TPB - 1) / TPB, TPB, 0, stream>>>(ei, deg, E, N);
    scan_partial<<<NB, 256, 0, stream>>>(deg, rowptr, bsums, N);
    scan_blocks<<<1, 64, 0, stream>>>(bsums, rowptr, NB, N);
    add_offsets<<<(N + TPB - 1) / TPB, TPB, 0, stream>>>(rowptr, bsums, N);
    scatter_edges<<<(Etot + TPB - 1) / TPB, TPB, 0, stream>>>(ei, rowptr, fill, srcs, E, N);

    // ---- casts ----
    int xt4 = N * F_IN / 4;
    xcast<<<(xt4 + TPB - 1) / TPB, TPB, 0, stream>>>(x, xb, xt4);
    wcast<<<(HC * F_IN + TPB - 1) / TPB, TPB, 0, stream>>>(W1, Wt1, F_IN, HC);
    wcast<<<(HC * HC + TPB - 1) / TPB, TPB, 0, stream>>>(W2, Wt2, HC, HC);
    wcast<<<(C * HC + TPB - 1) / TPB, TPB, 0, stream>>>(W3, Wt3, HC, C);

    dim3 gWide((HC + BN - 1) / BN, (N + BM - 1) / BM);
    dim3 gNarrow((C + BN - 1) / BN, (N + BM - 1) / BM);
    int waveBlocks = (N + 3) / 4;

    // ---- Layer 1 ----
    gemm_bf16<<<gWide, 256, 0, stream>>>(xb, Wt1, hA, a_src1, a_dst1, as_buf, ad_buf, N, HC, F_IN, 4);
    gat_aggregate<4, 4, false><<<waveBlocks, 256, 0, stream>>>(hA, as_buf, ad_buf, rowptr, srcs, b1, hB, N);

    // ---- Layer 2 ----
    gemm_bf16<<<gWide, 256, 0, stream>>>(hB, Wt2, hA, a_src2, a_dst2, as_buf, ad_buf, N, HC, HC, 4);
    gat_aggregate<4, 4, false><<<waveBlocks, 256, 0, stream>>>(hA, as_buf, ad_buf, rowptr, srcs, b2, hB, N);

    // ---- Layer 3 (H=1) ----
    gemm_bf16<<<gNarrow, 256, 0, stream>>>(hB, Wt3, hC, a_src3, a_dst3, as_buf, ad_buf, N, C, HC, 1);
    gat_aggregate<1, 1, true><<<waveBlocks, 256, 0, stream>>>(hC, as_buf, ad_buf, rowptr, srcs, b3, bufF, N);

    // ---- Pool + classify ----
    hipMemsetAsync(sums, 0, (size_t)(64 * 64 + 64) * 4, stream);
    pool_kernel<<<NPB, 256, 0, stream>>>(bufF, batch, sums, counts, N);
    classify<<<64, 256, 0, stream>>>(sums, counts, Wc, bc, (float*)d_out, NC);
}

// Round 11
// 454.197 us; speedup vs baseline: 1.4121x; 1.0451x over previous
//
#include <hip/hip_runtime.h>

// ---------------------------------------------------------------------------
// GAT 3-layer classifier, bf16 intermediate storage + MFMA GEMMs.
//   CSR build -> per layer: mfma-gemm(+attn epilogue) -> aggregate -> pool/cls
// R6: single-pass softmax (no max-shift), attn fused in GEMM, log2e fold.
// R8: aggregate = one wave/node, predicated unrolled gather rounds.
// R9 (REVERTED): head-slicing traded fill for 4x VALU -> lost. Aggregate
//     floor ~68us = per-XCD compulsory fill (208MB) + ~73% VALU; consistent
//     with L2 miss-concurrency limit.
// R10: GEMM staging via global_load_lds(16B) + XOR-swizzled LDS (no pad).
// R11: U=16 gather rounds in 4-head aggregates (deeper MLP vs miss latency);
//     atomic-free scatter via epos recorded in count pass (self-loops get
//     fixed last slot, +1 folded into scan); single fused cast kernel.
// ---------------------------------------------------------------------------

typedef __attribute__((ext_vector_type(8))) __bf16 bf16x8;
typedef __attribute__((ext_vector_type(4))) float f32x4;

#define LOG2E 1.44269504f

static __device__ __forceinline__ unsigned short f2bf(float f) {
    unsigned u = __float_as_uint(f);
    unsigned r = (u + 0x7fffu + ((u >> 16) & 1u)) >> 16;
    return (unsigned short)r;
}
static __device__ __forceinline__ float bf2f(unsigned short s) {
    return __uint_as_float(((unsigned)s) << 16);
}

static __device__ __forceinline__ void g2lds16(const unsigned short* g,
                                               unsigned short* l) {
    __builtin_amdgcn_global_load_lds(
        (const __attribute__((address_space(1))) unsigned int*)g,
        (__attribute__((address_space(3))) unsigned int*)l, 16, 0, 0);
}

// ============================ CSR build ====================================
// count real edges; record each edge's slot within its dst row.
__global__ void count_edges(const int* __restrict__ ei, int* __restrict__ deg,
                            int* __restrict__ epos, int E) {
    int i = blockIdx.x * blockDim.x + threadIdx.x;
    if (i >= E) return;
    int dst = ei[E + i];
    epos[i] = atomicAdd(&deg[dst], 1);
}

// exclusive scan of (deg[i]+1)  (+1 = self-loop appended at row end)
__global__ __launch_bounds__(256) void scan_partial(const int* __restrict__ deg,
                                                    int* __restrict__ rowptr,
                                                    int* __restrict__ blockSums, int N) {
    int t = threadIdx.x;
    int lane = t & 63, wv = t >> 6;
    int base = blockIdx.x * 1024 + t * 4;
    int v[4];
#pragma unroll
    for (int j = 0; j < 4; ++j) v[j] = (base + j < N) ? deg[base + j] + 1 : 0;
    int local = v[0] + v[1] + v[2] + v[3];
    int x = local;
#pragma unroll
    for (int off = 1; off < 64; off <<= 1) {
        int y = __shfl_up(x, off);
        if (lane >= off) x += y;
    }
    __shared__ int wsum[4];
    if (lane == 63) wsum[wv] = x;
    __syncthreads();
    int woff = 0;
    for (int i = 0; i < wv; ++i) woff += wsum[i];
    int run = woff + x - local;
#pragma unroll
    for (int j = 0; j < 4; ++j) {
        if (base + j < N) rowptr[base + j] = run;
        run += v[j];
    }
    if (t == 255) blockSums[blockIdx.x] = woff + x;
}

__global__ void scan_blocks(int* __restrict__ blockSums, int* __restrict__ rowptr,
                            int NB, int N) {
    int lane = threadIdx.x;  // 64 threads
    int carry = 0;
    for (int b0 = 0; b0 < NB; b0 += 64) {
        int i = b0 + lane;
        int v = (i < NB) ? blockSums[i] : 0;
        int x = v;
#pragma unroll
        for (int off = 1; off < 64; off <<= 1) {
            int y = __shfl_up(x, off);
            if (lane >= off) x += y;
        }
        if (i < NB) blockSums[i] = carry + x - v;
        carry += __shfl(x, 63);
    }
    if (lane == 0) rowptr[N] = carry;
}

__global__ void add_offsets(int* __restrict__ rowptr, const int* __restrict__ blockOffs,
                            int N) {
    int i = blockIdx.x * blockDim.x + threadIdx.x;
    if (i < N) rowptr[i] += blockOffs[i >> 10];
}

// atomic-free scatter: real edge i -> rowptr[dst]+epos[i]; self-loop of d ->
// rowptr[d]+deg[d] (last slot; deg excludes self-loops).
__global__ void scatter_edges(const int* __restrict__ ei, const int* __restrict__ rowptr,
                              const int* __restrict__ deg, const int* __restrict__ epos,
                              int* __restrict__ srcs, int E, int N) {
    int i = blockIdx.x * blockDim.x + threadIdx.x;
    int tot = E + N;
    if (i >= tot) return;
    if (i < E) {
        int dst = ei[E + i];
        srcs[rowptr[dst] + epos[i]] = ei[i];
    } else {
        int d = i - E;
        srcs[rowptr[d] + deg[d]] = d;
    }
}

// ============================ fused casts ==================================
// one launch: xb = bf16(x) [vec4]; Wt_l[n*K+k] = bf16(W_l[k*N+n]) for l=1..3
__global__ void prep_cast(const float* __restrict__ x, unsigned short* __restrict__ xb,
                          const float* __restrict__ W1, unsigned short* __restrict__ Wt1,
                          const float* __restrict__ W2, unsigned short* __restrict__ Wt2,
                          const float* __restrict__ W3, unsigned short* __restrict__ Wt3,
                          int n0, int n1, int n2, int n3,
                          int F_IN, int HC, int C) {
    int i = blockIdx.x * blockDim.x + threadIdx.x;
    if (i < n0) {
        float4 v = ((const float4*)x)[i];
        ushort4 o;
        o.x = f2bf(v.x); o.y = f2bf(v.y); o.z = f2bf(v.z); o.w = f2bf(v.w);
        ((ushort4*)xb)[i] = o;
        return;
    }
    i -= n0;
    if (i < n1) {  // Wt1: [HC][F_IN]
        int n = i / F_IN, k = i - n * F_IN;
        Wt1[i] = f2bf(W1[(size_t)k * HC + n]);
        return;
    }
    i -= n1;
    if (i < n2) {  // Wt2: [HC][HC]
        int n = i / HC, k = i - n * HC;
        Wt2[i] = f2bf(W2[(size_t)k * HC + n]);
        return;
    }
    i -= n2;
    if (i < n3) {  // Wt3: [C][HC]
        int n = i / HC, k = i - n * HC;
        Wt3[i] = f2bf(W3[(size_t)k * C + n]);
    }
}

// ============================ MFMA GEMM + attn epilogue ====================
// C[M,N](bf16) = A[M,K](bf16) @ Bt[N,K](bf16)^T.  128x128 tile, BK=32,
// 4 waves, 64x64/wave.  Staging via global_load_lds width=16 with XOR
// swizzle (seg^=(row>>1)&3) so fragment ds_read_b128 is 2-way-aliased (free).
// Epilogue: wave's 64-col span == one head; as/ad pre-scaled by log2(e).
#define BM 128
#define BN 128
#define BK 32

__global__ __launch_bounds__(256) void gemm_bf16(const unsigned short* __restrict__ A,
                                                 const unsigned short* __restrict__ Bt,
                                                 unsigned short* __restrict__ C,
                                                 const float* __restrict__ a_src,
                                                 const float* __restrict__ a_dst,
                                                 float* __restrict__ as_o,
                                                 float* __restrict__ ad_o,
                                                 int M, int N, int K, int H) {
    __shared__ unsigned short As[BM * BK];
    __shared__ unsigned short Bs[BN * BK];
    int t = threadIdx.x;
    int bm = blockIdx.y * BM, bn = blockIdx.x * BN;
    int wave = t >> 6, lane = t & 63;
    int wm = (wave >> 1) * 64, wn = (wave & 1) * 64;
    int quad = lane >> 4, mr = lane & 15;

    f32x4 zero = {0.f, 0.f, 0.f, 0.f};
    f32x4 acc[4][4];
#pragma unroll
    for (int i = 0; i < 4; ++i)
#pragma unroll
        for (int j = 0; j < 4; ++j) acc[i][j] = zero;

    int sw = quad ^ ((mr >> 1) & 3);
    int aoff[4], boff[4];
#pragma unroll
    for (int i = 0; i < 4; ++i) {
        aoff[i] = (wm + i * 16 + mr) * BK + sw * 8;
        boff[i] = (wn + i * 16 + mr) * BK + sw * 8;
    }

    for (int k0 = 0; k0 < K; k0 += BK) {
        __syncthreads();   // prior iteration's reads done before overwrite
#pragma unroll
        for (int h = 0; h < 2; ++h) {
            int slotbase = (wave * 2 + h) * 64;
            int slot = slotbase + lane;
            int row = slot >> 2;
            int sg = (slot & 3) ^ ((row >> 1) & 3);
            int gra = bm + row;
            if (gra < M)
                g2lds16(&A[(size_t)gra * K + k0 + sg * 8], &As[slotbase * 8]);
            int grb = bn + row;
            if (grb < N)
                g2lds16(&Bt[(size_t)grb * K + k0 + sg * 8], &Bs[slotbase * 8]);
        }
        __syncthreads();

        bf16x8 af[4], bfr[4];
#pragma unroll
        for (int i = 0; i < 4; ++i) {
            af[i]  = *(bf16x8*)&As[aoff[i]];
            bfr[i] = *(bf16x8*)&Bs[boff[i]];
        }
#pragma unroll
        for (int i = 0; i < 4; ++i)
#pragma unroll
            for (int j = 0; j < 4; ++j)
                acc[i][j] = __builtin_amdgcn_mfma_f32_16x16x32_bf16(af[i], bfr[j], acc[i][j], 0, 0, 0);
    }

    // attn coefficients: this wave's 64 cols == head (bn+wn)/64
    int colbase = bn + wn;
    if (colbase + 64 <= N) {
        int head = colbase >> 6;
        float asv[4], adv[4];
#pragma unroll
        for (int j = 0; j < 4; ++j) {
            asv[j] = a_src[head * 64 + j * 16 + mr];
            adv[j] = a_dst[head * 64 + j * 16 + mr];
        }
#pragma unroll
        for (int i = 0; i < 4; ++i) {
#pragma unroll
            for (int r = 0; r < 4; ++r) {
                float ps = acc[i][0][r] * asv[0] + acc[i][1][r] * asv[1]
                         + acc[i][2][r] * asv[2] + acc[i][3][r] * asv[3];
                float pd = acc[i][0][r] * adv[0] + acc[i][1][r] * adv[1]
                         + acc[i][2][r] * adv[2] + acc[i][3][r] * adv[3];
#pragma unroll
                for (int off2 = 1; off2 < 16; off2 <<= 1) {
                    ps += __shfl_xor(ps, off2);
                    pd += __shfl_xor(pd, off2);
                }
                int grow = bm + wm + i * 16 + quad * 4 + r;
                if (mr == 0 && grow < M) {
                    as_o[(size_t)grow * H + head] = ps * LOG2E;
                    ad_o[(size_t)grow * H + head] = pd * LOG2E;
                }
            }
        }
    }

    // C store: C/D layout col=lane&15, row=quad*4+reg
#pragma unroll
    for (int i = 0; i < 4; ++i) {
#pragma unroll
        for (int r = 0; r < 4; ++r) {
            int grow = bm + wm + i * 16 + quad * 4 + r;
            if (grow >= M) continue;
#pragma unroll
            for (int j = 0; j < 4; ++j) {
                int gcol = bn + wn + j * 16 + mr;
                if (gcol < N) C[(size_t)grow * N + gcol] = f2bf(acc[i][j][r]);
            }
        }
    }
}

// ============================ aggregation ==================================
// Single-pass unnormalized softmax: out = sum(exp(e)*h) / (sum(exp(e))+eps).
// as/ad pre-scaled by log2(e) -> exp2 in the hot loop.
// One wave per node; predicated U-deep unrolled gather rounds.
// U=16 for 4-head layers (avg degree ~17 -> mostly one round), U=8 for H=1.
template <int H, int VPL, bool OUTF32, int U>
__global__ __launch_bounds__(256) void gat_aggregate(const unsigned short* __restrict__ hbuf,
                                                     const float* __restrict__ as_i,
                                                     const float* __restrict__ ad_i,
                                                     const int* __restrict__ rowptr,
                                                     const int* __restrict__ srcs,
                                                     const float* __restrict__ bias,
                                                     void* __restrict__ out_v, int N) {
    const int HC = 64 * VPL;
    int node = (blockIdx.x * blockDim.x + threadIdx.x) >> 6;
    int lane = threadIdx.x & 63;
    if (node >= N) return;
    int row = rowptr[node], end = rowptr[node + 1];
    int len = end - row;
    const int hd_lane = (lane * VPL) >> 6;

    float advh = ad_i[(size_t)node * H + hd_lane];

    float acc[VPL];
#pragma unroll
    for (int j = 0; j < VPL; ++j) acc[j] = 0.f;
    float l = 0.f;

    for (int base = 0; base < len; base += U) {
        int s[U];
        float cf[U];
#pragma unroll
        for (int u = 0; u < U; ++u) {
            int idx = base + u;
            int ii = row + ((idx < len) ? idx : (len - 1));
            s[u] = srcs[ii];
        }
#pragma unroll
        for (int u = 0; u < U; ++u) cf[u] = as_i[(size_t)s[u] * H + hd_lane];
        if (VPL == 4) {
            ushort4 r[U];
#pragma unroll
            for (int u = 0; u < U; ++u)
                r[u] = *(const ushort4*)&hbuf[(size_t)s[u] * HC + lane * 4];
#pragma unroll
            for (int u = 0; u < U; ++u) {
                float e = cf[u] + advh;
                e = (e > 0.f) ? e : 0.2f * e;
                float wgt = (base + u < len) ? exp2f(e) : 0.f;
                l += wgt;
                acc[0] += wgt * bf2f(r[u].x);
                acc[1] += wgt * bf2f(r[u].y);
                acc[2] += wgt * bf2f(r[u].z);
                acc[3] += wgt * bf2f(r[u].w);
            }
        } else {
            unsigned short r[U];
#pragma unroll
            for (int u = 0; u < U; ++u) r[u] = hbuf[(size_t)s[u] * HC + lane];
#pragma unroll
            for (int u = 0; u < U; ++u) {
                float e = cf[u] + advh;
                e = (e > 0.f) ? e : 0.2f * e;
                float wgt = (base + u < len) ? exp2f(e) : 0.f;
                l += wgt;
                acc[0] += wgt * bf2f(r[u]);
            }
        }
    }

    float inv_l = 1.f / (l + 1e-16f);
    float vals[VPL];
#pragma unroll
    for (int j = 0; j < VPL; ++j) {
        float v = acc[j] * inv_l + bias[lane * VPL + j];
        vals[j] = (v > 0.f) ? v : (__expf(v) - 1.f);
    }
    if (OUTF32) {
        float* out = (float*)out_v;
#pragma unroll
        for (int j = 0; j < VPL; ++j)
            out[(size_t)node * HC + lane * VPL + j] = vals[j];
    } else {
        unsigned short* out = (unsigned short*)out_v;
        if (VPL == 4) {
            ushort4 o;
            o.x = f2bf(vals[0]); o.y = f2bf(vals[1]);
            o.z = f2bf(vals[2]); o.w = f2bf(vals[3]);
            *(ushort4*)&out[(size_t)node * HC + lane * 4] = o;
        } else {
            out[(size_t)node * HC + lane] = f2bf(vals[0]);
        }
    }
}

// ============================ pool + classify ==============================
#define POOL_CHUNK 128
__global__ __launch_bounds__(256) void pool_kernel(const float* __restrict__ hf,
                                                   const int* __restrict__ batch,
                                                   float* __restrict__ sums,
                                                   float* __restrict__ counts, int N) {
    int t = threadIdx.x;
    int c = t & 63, sub = t >> 6;
    int start = blockIdx.x * POOL_CHUNK;
    int end = min(start + POOL_CHUNK, N);
    float acc = 0.f, cnt = 0.f;
    int cur = -1;
    for (int n = start + sub; n < end; n += 4) {
        int g = batch[n];
        if (g != cur) {
            if (cur >= 0) {
                atomicAdd(&sums[cur * 64 + c], acc);
                if (c == 0) atomicAdd(&counts[cur], cnt);
            }
            cur = g; acc = 0.f; cnt = 0.f;
        }
        acc += hf[(size_t)n * 64 + c];
        cnt += 1.f;
    }
    if (cur >= 0) {
        atomicAdd(&sums[cur * 64 + c], acc);
        if (c == 0) atomicAdd(&counts[cur], cnt);
    }
}

__global__ void classify(const float* __restrict__ sums, const float* __restrict__ counts,
                         const float* __restrict__ Wc, const float* __restrict__ bc,
                         float* __restrict__ out, int NC) {
    __shared__ float p[64];
    int g = blockIdx.x;
    if (threadIdx.x < 64) {
        float cnt = fmaxf(counts[g], 1.0f);
        p[threadIdx.x] = sums[g * 64 + threadIdx.x] / cnt;
    }
    __syncthreads();
    int k = threadIdx.x;
    if (k < NC) {
        float acc = bc[k];
        for (int c = 0; c < 64; ++c) acc += p[c] * Wc[c * NC + k];
        out[g * NC + k] = acc;
    }
}

static inline size_t align_up(size_t x, size_t a) { return (x + a - 1) / a * a; }

extern "C" void kernel_launch(void* const* d_in, const int* in_sizes, int n_in,
                              void* d_out, int out_size, void* d_ws, size_t ws_size,
                              hipStream_t stream) {
    const float* x      = (const float*)d_in[0];
    const int*   ei     = (const int*)d_in[1];
    const int*   batch  = (const int*)d_in[2];
    const float* W1     = (const float*)d_in[3];
    const float* a_src1 = (const float*)d_in[4];
    const float* a_dst1 = (const float*)d_in[5];
    const float* b1     = (const float*)d_in[6];
    const float* W2     = (const float*)d_in[7];
    const float* a_src2 = (const float*)d_in[8];
    const float* a_dst2 = (const float*)d_in[9];
    const float* b2     = (const float*)d_in[10];
    const float* W3     = (const float*)d_in[11];
    const float* a_src3 = (const float*)d_in[12];
    const float* a_dst3 = (const float*)d_in[13];
    const float* b3     = (const float*)d_in[14];
    const float* Wc     = (const float*)d_in[15];
    const float* bc     = (const float*)d_in[16];

    const int N    = in_sizes[2];
    const int E    = in_sizes[1] / 2;
    const int F_IN = in_sizes[0] / N;   // 128
    const int HC   = in_sizes[6];       // 256
    const int C    = in_sizes[14];      // 64
    const int NC   = in_sizes[16];      // 200
    const int Etot = E + N;
    const int NB   = (N + 1023) / 1024;
    const int NPB  = (N + POOL_CHUNK - 1) / POOL_CHUNK;

    char* w = (char*)d_ws;
    size_t off = 0;
    auto alloc = [&](size_t bytes) -> void* {
        void* p = w + off;
        off = align_up(off + bytes, 256);
        return p;
    };
    int*   deg    = (int*)alloc((size_t)N * 4);
    int*   rowptr = (int*)alloc((size_t)(N + 1) * 4);
    int*   epos   = (int*)alloc((size_t)E * 4);
    int*   srcs   = (int*)alloc((size_t)Etot * 4);
    int*   bsums  = (int*)alloc((size_t)NB * 4);
    float* as_buf = (float*)alloc((size_t)N * 4 * 4);
    float* ad_buf = (float*)alloc((size_t)N * 4 * 4);
    unsigned short* xb  = (unsigned short*)alloc((size_t)N * F_IN * 2);
    unsigned short* Wt1 = (unsigned short*)alloc((size_t)HC * F_IN * 2);
    unsigned short* Wt2 = (unsigned short*)alloc((size_t)HC * HC * 2);
    unsigned short* Wt3 = (unsigned short*)alloc((size_t)C * HC * 2);
    unsigned short* hA  = (unsigned short*)alloc((size_t)N * HC * 2);
    unsigned short* hB  = (unsigned short*)alloc((size_t)N * HC * 2);
    unsigned short* hC  = (unsigned short*)alloc((size_t)N * C * 2);
    float* bufF   = (float*)alloc((size_t)N * C * 4);
    float* sums   = (float*)alloc((size_t)(64 * 64 + 64) * 4);
    float* counts = sums + 64 * 64;

    const int TPB = 256;

    // ---- CSR build (atomic-free scatter) ----
    hipMemsetAsync(deg, 0, (size_t)N * 4, stream);
    count_edges<<<(E + TPB - 1) / TPB, TPB, 0, stream>>>(ei, deg, epos, E);
    scan_partial<<<NB, 256, 0, stream>>>(deg, rowptr, bsums, N);
    scan_blocks<<<1, 64, 0, stream>>>(bsums, rowptr, NB, N);
    add_offsets<<<(N + TPB - 1) / TPB, TPB, 0, stream>>>(rowptr, bsums, N);
    scatter_edges<<<(Etot + TPB - 1) / TPB, TPB, 0, stream>>>(ei, rowptr, deg, epos, srcs, E, N);

    // ---- fused casts (1 launch) ----
    int n0 = N * F_IN / 4, n1 = HC * F_IN, n2 = HC * HC, n3 = C * HC;
    int ntot = n0 + n1 + n2 + n3;
    prep_cast<<<(ntot + TPB - 1) / TPB, TPB, 0, stream>>>(
        x, xb, W1, Wt1, W2, Wt2, W3, Wt3, n0, n1, n2, n3, F_IN, HC, C);

    dim3 gWide((HC + BN - 1) / BN, (N + BM - 1) / BM);
    dim3 gNarrow((C + BN - 1) / BN, (N + BM - 1) / BM);
    int waveBlocks = (N + 3) / 4;

    // ---- Layer 1 ----
    gemm_bf16<<<gWide, 256, 0, stream>>>(xb, Wt1, hA, a_src1, a_dst1, as_buf, ad_buf, N, HC, F_IN, 4);
    gat_aggregate<4, 4, false, 16><<<waveBlocks, 256, 0, stream>>>(hA, as_buf, ad_buf, rowptr, srcs, b1, hB, N);

    // ---- Layer 2 ----
    gemm_bf16<<<gWide, 256, 0, stream>>>(hB, Wt2, hA, a_src2, a_dst2, as_buf, ad_buf, N, HC, HC, 4);
    gat_aggregate<4, 4, false, 16><<<waveBlocks, 256, 0, stream>>>(hA, as_buf, ad_buf, rowptr, srcs, b2, hB, N);

    // ---- Layer 3 (H=1) ----
    gemm_bf16<<<gNarrow, 256, 0, stream>>>(hB, Wt3, hC, a_src3, a_dst3, as_buf, ad_buf, N, C, HC, 1);
    gat_aggregate<1, 1, true, 8><<<waveBlocks, 256, 0, stream>>>(hC, as_buf, ad_buf, rowptr, srcs, b3, bufF, N);

    // ---- Pool + classify ----
    hipMemsetAsync(sums, 0, (size_t)(64 * 64 + 64) * 4, stream);
    pool_kernel<<<NPB, 256, 0, stream>>>(bufF, batch, sums, counts, N);
    classify<<<64, 256, 0, stream>>>(sums, counts, Wc, bc, (float*)d_out, NC);
}

// Round 12
// 439.287 us; speedup vs baseline: 1.4600x; 1.0339x over previous
//
#include <hip/hip_runtime.h>

// ---------------------------------------------------------------------------
// GAT 3-layer classifier, bf16 intermediate storage + MFMA GEMMs.
//   CSR build -> per layer: mfma-gemm(+attn epilogue) -> aggregate -> pool/cls
// R6: single-pass softmax (no max-shift), attn fused in GEMM, log2e fold.
// R8: aggregate = one wave/node, predicated unrolled gather rounds.
// R9 (REVERTED): head-slicing traded fill for 4x VALU -> lost.
// R10: GEMM staging via global_load_lds(16B) + XOR-swizzled LDS (no pad).
// R11: atomic-free scatter (epos from count pass; self-loop in last slot,
//      +1 folded into scan); single fused cast kernel.  U=16 REVERTED:
//      predicated loads still issue -> 88% clamp-duplicate gathers in round 2
//      at deg~17, occupancy 66->42% (VGPR 48); agg 68.5->82.5us.
// R12: U=8 everywhere. Aggregate floor (5 experiments): ~68us = 208MB
//      compulsory per-XCD L2 fill + ~73% VALU issue, one wave/node, U=8.
// ---------------------------------------------------------------------------

typedef __attribute__((ext_vector_type(8))) __bf16 bf16x8;
typedef __attribute__((ext_vector_type(4))) float f32x4;

#define LOG2E 1.44269504f

static __device__ __forceinline__ unsigned short f2bf(float f) {
    unsigned u = __float_as_uint(f);
    unsigned r = (u + 0x7fffu + ((u >> 16) & 1u)) >> 16;
    return (unsigned short)r;
}
static __device__ __forceinline__ float bf2f(unsigned short s) {
    return __uint_as_float(((unsigned)s) << 16);
}

static __device__ __forceinline__ void g2lds16(const unsigned short* g,
                                               unsigned short* l) {
    __builtin_amdgcn_global_load_lds(
        (const __attribute__((address_space(1))) unsigned int*)g,
        (__attribute__((address_space(3))) unsigned int*)l, 16, 0, 0);
}

// ============================ CSR build ====================================
__global__ void count_edges(const int* __restrict__ ei, int* __restrict__ deg,
                            int* __restrict__ epos, int E) {
    int i = blockIdx.x * blockDim.x + threadIdx.x;
    if (i >= E) return;
    int dst = ei[E + i];
    epos[i] = atomicAdd(&deg[dst], 1);
}

// exclusive scan of (deg[i]+1)  (+1 = self-loop appended at row end)
__global__ __launch_bounds__(256) void scan_partial(const int* __restrict__ deg,
                                                    int* __restrict__ rowptr,
                                                    int* __restrict__ blockSums, int N) {
    int t = threadIdx.x;
    int lane = t & 63, wv = t >> 6;
    int base = blockIdx.x * 1024 + t * 4;
    int v[4];
#pragma unroll
    for (int j = 0; j < 4; ++j) v[j] = (base + j < N) ? deg[base + j] + 1 : 0;
    int local = v[0] + v[1] + v[2] + v[3];
    int x = local;
#pragma unroll
    for (int off = 1; off < 64; off <<= 1) {
        int y = __shfl_up(x, off);
        if (lane >= off) x += y;
    }
    __shared__ int wsum[4];
    if (lane == 63) wsum[wv] = x;
    __syncthreads();
    int woff = 0;
    for (int i = 0; i < wv; ++i) woff += wsum[i];
    int run = woff + x - local;
#pragma unroll
    for (int j = 0; j < 4; ++j) {
        if (base + j < N) rowptr[base + j] = run;
        run += v[j];
    }
    if (t == 255) blockSums[blockIdx.x] = woff + x;
}

__global__ void scan_blocks(int* __restrict__ blockSums, int* __restrict__ rowptr,
                            int NB, int N) {
    int lane = threadIdx.x;  // 64 threads
    int carry = 0;
    for (int b0 = 0; b0 < NB; b0 += 64) {
        int i = b0 + lane;
        int v = (i < NB) ? blockSums[i] : 0;
        int x = v;
#pragma unroll
        for (int off = 1; off < 64; off <<= 1) {
            int y = __shfl_up(x, off);
            if (lane >= off) x += y;
        }
        if (i < NB) blockSums[i] = carry + x - v;
        carry += __shfl(x, 63);
    }
    if (lane == 0) rowptr[N] = carry;
}

__global__ void add_offsets(int* __restrict__ rowptr, const int* __restrict__ blockOffs,
                            int N) {
    int i = blockIdx.x * blockDim.x + threadIdx.x;
    if (i < N) rowptr[i] += blockOffs[i >> 10];
}

// atomic-free scatter: real edge i -> rowptr[dst]+epos[i]; self-loop of d ->
// rowptr[d]+deg[d] (last slot; deg excludes self-loops).
__global__ void scatter_edges(const int* __restrict__ ei, const int* __restrict__ rowptr,
                              const int* __restrict__ deg, const int* __restrict__ epos,
                              int* __restrict__ srcs, int E, int N) {
    int i = blockIdx.x * blockDim.x + threadIdx.x;
    int tot = E + N;
    if (i >= tot) return;
    if (i < E) {
        int dst = ei[E + i];
        srcs[rowptr[dst] + epos[i]] = ei[i];
    } else {
        int d = i - E;
        srcs[rowptr[d] + deg[d]] = d;
    }
}

// ============================ fused casts ==================================
__global__ void prep_cast(const float* __restrict__ x, unsigned short* __restrict__ xb,
                          const float* __restrict__ W1, unsigned short* __restrict__ Wt1,
                          const float* __restrict__ W2, unsigned short* __restrict__ Wt2,
                          const float* __restrict__ W3, unsigned short* __restrict__ Wt3,
                          int n0, int n1, int n2, int n3,
                          int F_IN, int HC, int C) {
    int i = blockIdx.x * blockDim.x + threadIdx.x;
    if (i < n0) {
        float4 v = ((const float4*)x)[i];
        ushort4 o;
        o.x = f2bf(v.x); o.y = f2bf(v.y); o.z = f2bf(v.z); o.w = f2bf(v.w);
        ((ushort4*)xb)[i] = o;
        return;
    }
    i -= n0;
    if (i < n1) {  // Wt1: [HC][F_IN]
        int n = i / F_IN, k = i - n * F_IN;
        Wt1[i] = f2bf(W1[(size_t)k * HC + n]);
        return;
    }
    i -= n1;
    if (i < n2) {  // Wt2: [HC][HC]
        int n = i / HC, k = i - n * HC;
        Wt2[i] = f2bf(W2[(size_t)k * HC + n]);
        return;
    }
    i -= n2;
    if (i < n3) {  // Wt3: [C][HC]
        int n = i / HC, k = i - n * HC;
        Wt3[i] = f2bf(W3[(size_t)k * C + n]);
    }
}

// ============================ MFMA GEMM + attn epilogue ====================
// C[M,N](bf16) = A[M,K](bf16) @ Bt[N,K](bf16)^T.  128x128 tile, BK=32,
// 4 waves, 64x64/wave.  Staging via global_load_lds width=16 with XOR
// swizzle (seg^=(row>>1)&3) so fragment ds_read_b128 is 2-way-aliased (free).
// Epilogue: wave's 64-col span == one head; as/ad pre-scaled by log2(e).
#define BM 128
#define BN 128
#define BK 32

__global__ __launch_bounds__(256) void gemm_bf16(const unsigned short* __restrict__ A,
                                                 const unsigned short* __restrict__ Bt,
                                                 unsigned short* __restrict__ C,
                                                 const float* __restrict__ a_src,
                                                 const float* __restrict__ a_dst,
                                                 float* __restrict__ as_o,
                                                 float* __restrict__ ad_o,
                                                 int M, int N, int K, int H) {
    __shared__ unsigned short As[BM * BK];
    __shared__ unsigned short Bs[BN * BK];
    int t = threadIdx.x;
    int bm = blockIdx.y * BM, bn = blockIdx.x * BN;
    int wave = t >> 6, lane = t & 63;
    int wm = (wave >> 1) * 64, wn = (wave & 1) * 64;
    int quad = lane >> 4, mr = lane & 15;

    f32x4 zero = {0.f, 0.f, 0.f, 0.f};
    f32x4 acc[4][4];
#pragma unroll
    for (int i = 0; i < 4; ++i)
#pragma unroll
        for (int j = 0; j < 4; ++j) acc[i][j] = zero;

    int sw = quad ^ ((mr >> 1) & 3);
    int aoff[4], boff[4];
#pragma unroll
    for (int i = 0; i < 4; ++i) {
        aoff[i] = (wm + i * 16 + mr) * BK + sw * 8;
        boff[i] = (wn + i * 16 + mr) * BK + sw * 8;
    }

    for (int k0 = 0; k0 < K; k0 += BK) {
        __syncthreads();   // prior iteration's reads done before overwrite
#pragma unroll
        for (int h = 0; h < 2; ++h) {
            int slotbase = (wave * 2 + h) * 64;
            int slot = slotbase + lane;
            int row = slot >> 2;
            int sg = (slot & 3) ^ ((row >> 1) & 3);
            int gra = bm + row;
            if (gra < M)
                g2lds16(&A[(size_t)gra * K + k0 + sg * 8], &As[slotbase * 8]);
            int grb = bn + row;
            if (grb < N)
                g2lds16(&Bt[(size_t)grb * K + k0 + sg * 8], &Bs[slotbase * 8]);
        }
        __syncthreads();

        bf16x8 af[4], bfr[4];
#pragma unroll
        for (int i = 0; i < 4; ++i) {
            af[i]  = *(bf16x8*)&As[aoff[i]];
            bfr[i] = *(bf16x8*)&Bs[boff[i]];
        }
#pragma unroll
        for (int i = 0; i < 4; ++i)
#pragma unroll
            for (int j = 0; j < 4; ++j)
                acc[i][j] = __builtin_amdgcn_mfma_f32_16x16x32_bf16(af[i], bfr[j], acc[i][j], 0, 0, 0);
    }

    // attn coefficients: this wave's 64 cols == head (bn+wn)/64
    int colbase = bn + wn;
    if (colbase + 64 <= N) {
        int head = colbase >> 6;
        float asv[4], adv[4];
#pragma unroll
        for (int j = 0; j < 4; ++j) {
            asv[j] = a_src[head * 64 + j * 16 + mr];
            adv[j] = a_dst[head * 64 + j * 16 + mr];
        }
#pragma unroll
        for (int i = 0; i < 4; ++i) {
#pragma unroll
            for (int r = 0; r < 4; ++r) {
                float ps = acc[i][0][r] * asv[0] + acc[i][1][r] * asv[1]
                         + acc[i][2][r] * asv[2] + acc[i][3][r] * asv[3];
                float pd = acc[i][0][r] * adv[0] + acc[i][1][r] * adv[1]
                         + acc[i][2][r] * adv[2] + acc[i][3][r] * adv[3];
#pragma unroll
                for (int off2 = 1; off2 < 16; off2 <<= 1) {
                    ps += __shfl_xor(ps, off2);
                    pd += __shfl_xor(pd, off2);
                }
                int grow = bm + wm + i * 16 + quad * 4 + r;
                if (mr == 0 && grow < M) {
                    as_o[(size_t)grow * H + head] = ps * LOG2E;
                    ad_o[(size_t)grow * H + head] = pd * LOG2E;
                }
            }
        }
    }

    // C store: C/D layout col=lane&15, row=quad*4+reg
#pragma unroll
    for (int i = 0; i < 4; ++i) {
#pragma unroll
        for (int r = 0; r < 4; ++r) {
            int grow = bm + wm + i * 16 + quad * 4 + r;
            if (grow >= M) continue;
#pragma unroll
            for (int j = 0; j < 4; ++j) {
                int gcol = bn + wn + j * 16 + mr;
                if (gcol < N) C[(size_t)grow * N + gcol] = f2bf(acc[i][j][r]);
            }
        }
    }
}

// ============================ aggregation ==================================
// Single-pass unnormalized softmax: out = sum(exp(e)*h) / (sum(exp(e))+eps).
// as/ad pre-scaled by log2(e) -> exp2 in the hot loop.
// One wave per node; predicated 8-deep unrolled gather rounds (U=8 is the
// measured optimum: 4->120us, 8->68.5us, 16->82.5us).
template <int H, int VPL, bool OUTF32>
__global__ __launch_bounds__(256) void gat_aggregate(const unsigned short* __restrict__ hbuf,
                                                     const float* __restrict__ as_i,
                                                     const float* __restrict__ ad_i,
                                                     const int* __restrict__ rowptr,
                                                     const int* __restrict__ srcs,
                                                     const float* __restrict__ bias,
                                                     void* __restrict__ out_v, int N) {
    const int HC = 64 * VPL;
    int node = (blockIdx.x * blockDim.x + threadIdx.x) >> 6;
    int lane = threadIdx.x & 63;
    if (node >= N) return;
    int row = rowptr[node], end = rowptr[node + 1];
    int len = end - row;
    const int hd_lane = (lane * VPL) >> 6;

    float advh = ad_i[(size_t)node * H + hd_lane];

    float acc[VPL];
#pragma unroll
    for (int j = 0; j < VPL; ++j) acc[j] = 0.f;
    float l = 0.f;

    const int U = 8;
    for (int base = 0; base < len; base += U) {
        int s[U];
        float cf[U];
#pragma unroll
        for (int u = 0; u < U; ++u) {
            int idx = base + u;
            int ii = row + ((idx < len) ? idx : (len - 1));
            s[u] = srcs[ii];
        }
#pragma unroll
        for (int u = 0; u < U; ++u) cf[u] = as_i[(size_t)s[u] * H + hd_lane];
        if (VPL == 4) {
            ushort4 r[U];
#pragma unroll
            for (int u = 0; u < U; ++u)
                r[u] = *(const ushort4*)&hbuf[(size_t)s[u] * HC + lane * 4];
#pragma unroll
            for (int u = 0; u < U; ++u) {
                float e = cf[u] + advh;
                e = (e > 0.f) ? e : 0.2f * e;
                float wgt = (base + u < len) ? exp2f(e) : 0.f;
                l += wgt;
                acc[0] += wgt * bf2f(r[u].x);
                acc[1] += wgt * bf2f(r[u].y);
                acc[2] += wgt * bf2f(r[u].z);
                acc[3] += wgt * bf2f(r[u].w);
            }
        } else {
            unsigned short r[U];
#pragma unroll
            for (int u = 0; u < U; ++u) r[u] = hbuf[(size_t)s[u] * HC + lane];
#pragma unroll
            for (int u = 0; u < U; ++u) {
                float e = cf[u] + advh;
                e = (e > 0.f) ? e : 0.2f * e;
                float wgt = (base + u < len) ? exp2f(e) : 0.f;
                l += wgt;
                acc[0] += wgt * bf2f(r[u]);
            }
        }
    }

    float inv_l = 1.f / (l + 1e-16f);
    float vals[VPL];
#pragma unroll
    for (int j = 0; j < VPL; ++j) {
        float v = acc[j] * inv_l + bias[lane * VPL + j];
        vals[j] = (v > 0.f) ? v : (__expf(v) - 1.f);
    }
    if (OUTF32) {
        float* out = (float*)out_v;
#pragma unroll
        for (int j = 0; j < VPL; ++j)
            out[(size_t)node * HC + lane * VPL + j] = vals[j];
    } else {
        unsigned short* out = (unsigned short*)out_v;
        if (VPL == 4) {
            ushort4 o;
            o.x = f2bf(vals[0]); o.y = f2bf(vals[1]);
            o.z = f2bf(vals[2]); o.w = f2bf(vals[3]);
            *(ushort4*)&out[(size_t)node * HC + lane * 4] = o;
        } else {
            out[(size_t)node * HC + lane] = f2bf(vals[0]);
        }
    }
}

// ============================ pool + classify ==============================
#define POOL_CHUNK 128
__global__ __launch_bounds__(256) void pool_kernel(const float* __restrict__ hf,
                                                   const int* __restrict__ batch,
                                                   float* __restrict__ sums,
                                                   float* __restrict__ counts, int N) {
    int t = threadIdx.x;
    int c = t & 63, sub = t >> 6;
    int start = blockIdx.x * POOL_CHUNK;
    int end = min(start + POOL_CHUNK, N);
    float acc = 0.f, cnt = 0.f;
    int cur = -1;
    for (int n = start + sub; n < end; n += 4) {
        int g = batch[n];
        if (g != cur) {
            if (cur >= 0) {
                atomicAdd(&sums[cur * 64 + c], acc);
                if (c == 0) atomicAdd(&counts[cur], cnt);
            }
            cur = g; acc = 0.f; cnt = 0.f;
        }
        acc += hf[(size_t)n * 64 + c];
        cnt += 1.f;
    }
    if (cur >= 0) {
        atomicAdd(&sums[cur * 64 + c], acc);
        if (c == 0) atomicAdd(&counts[cur], cnt);
    }
}

__global__ void classify(const float* __restrict__ sums, const float* __restrict__ counts,
                         const float* __restrict__ Wc, const float* __restrict__ bc,
                         float* __restrict__ out, int NC) {
    __shared__ float p[64];
    int g = blockIdx.x;
    if (threadIdx.x < 64) {
        float cnt = fmaxf(counts[g], 1.0f);
        p[threadIdx.x] = sums[g * 64 + threadIdx.x] / cnt;
    }
    __syncthreads();
    int k = threadIdx.x;
    if (k < NC) {
        float acc = bc[k];
        for (int c = 0; c < 64; ++c) acc += p[c] * Wc[c * NC + k];
        out[g * NC + k] = acc;
    }
}

static inline size_t align_up(size_t x, size_t a) { return (x + a - 1) / a * a; }

extern "C" void kernel_launch(void* const* d_in, const int* in_sizes, int n_in,
                              void* d_out, int out_size, void* d_ws, size_t ws_size,
                              hipStream_t stream) {
    const float* x      = (const float*)d_in[0];
    const int*   ei     = (const int*)d_in[1];
    const int*   batch  = (const int*)d_in[2];
    const float* W1     = (const float*)d_in[3];
    const float* a_src1 = (const float*)d_in[4];
    const float* a_dst1 = (const float*)d_in[5];
    const float* b1     = (const float*)d_in[6];
    const float* W2     = (const float*)d_in[7];
    const float* a_src2 = (const float*)d_in[8];
    const float* a_dst2 = (const float*)d_in[9];
    const float* b2     = (const float*)d_in[10];
    const float* W3     = (const float*)d_in[11];
    const float* a_src3 = (const float*)d_in[12];
    const float* a_dst3 = (const float*)d_in[13];
    const float* b3     = (const float*)d_in[14];
    const float* Wc     = (const float*)d_in[15];
    const float* bc     = (const float*)d_in[16];

    const int N    = in_sizes[2];
    const int E    = in_sizes[1] / 2;
    const int F_IN = in_sizes[0] / N;   // 128
    const int HC   = in_sizes[6];       // 256
    const int C    = in_sizes[14];      // 64
    const int NC   = in_sizes[16];      // 200
    const int Etot = E + N;
    const int NB   = (N + 1023) / 1024;
    const int NPB  = (N + POOL_CHUNK - 1) / POOL_CHUNK;

    char* w = (char*)d_ws;
    size_t off = 0;
    auto alloc = [&](size_t bytes) -> void* {
        void* p = w + off;
        off = align_up(off + bytes, 256);
        return p;
    };
    int*   deg    = (int*)alloc((size_t)N * 4);
    int*   rowptr = (int*)alloc((size_t)(N + 1) * 4);
    int*   epos   = (int*)alloc((size_t)E * 4);
    int*   srcs   = (int*)alloc((size_t)Etot * 4);
    int*   bsums  = (int*)alloc((size_t)NB * 4);
    float* as_buf = (float*)alloc((size_t)N * 4 * 4);
    float* ad_buf = (float*)alloc((size_t)N * 4 * 4);
    unsigned short* xb  = (unsigned short*)alloc((size_t)N * F_IN * 2);
    unsigned short* Wt1 = (unsigned short*)alloc((size_t)HC * F_IN * 2);
    unsigned short* Wt2 = (unsigned short*)alloc((size_t)HC * HC * 2);
    unsigned short* Wt3 = (unsigned short*)alloc((size_t)C * HC * 2);
    unsigned short* hA  = (unsigned short*)alloc((size_t)N * HC * 2);
    unsigned short* hB  = (unsigned short*)alloc((size_t)N * HC * 2);
    unsigned short* hC  = (unsigned short*)alloc((size_t)N * C * 2);
    float* bufF   = (float*)alloc((size_t)N * C * 4);
    float* sums   = (float*)alloc((size_t)(64 * 64 + 64) * 4);
    float* counts = sums + 64 * 64;

    const int TPB = 256;

    // ---- CSR build (atomic-free scatter) ----
    hipMemsetAsync(deg, 0, (size_t)N * 4, stream);
    count_edges<<<(E + TPB - 1) / TPB, TPB, 0, stream>>>(ei, deg, epos, E);
    scan_partial<<<NB, 256, 0, stream>>>(deg, rowptr, bsums, N);
    scan_blocks<<<1, 64, 0, stream>>>(bsums, rowptr, NB, N);
    add_offsets<<<(N + TPB - 1) / TPB, TPB, 0, stream>>>(rowptr, bsums, N);
    scatter_edges<<<(Etot + TPB - 1) / TPB, TPB, 0, stream>>>(ei, rowptr, deg, epos, srcs, E, N);

    // ---- fused casts (1 launch) ----
    int n0 = N * F_IN / 4, n1 = HC * F_IN, n2 = HC * HC, n3 = C * HC;
    int ntot = n0 + n1 + n2 + n3;
    prep_cast<<<(ntot + TPB - 1) / TPB, TPB, 0, stream>>>(
        x, xb, W1, Wt1, W2, Wt2, W3, Wt3, n0, n1, n2, n3, F_IN, HC, C);

    dim3 gWide((HC + BN - 1) / BN, (N + BM - 1) / BM);
    dim3 gNarrow((C + BN - 1) / BN, (N + BM - 1) / BM);
    int waveBlocks = (N + 3) / 4;

    // ---- Layer 1 ----
    gemm_bf16<<<gWide, 256, 0, stream>>>(xb, Wt1, hA, a_src1, a_dst1, as_buf, ad_buf, N, HC, F_IN, 4);
    gat_aggregate<4, 4, false><<<waveBlocks, 256, 0, stream>>>(hA, as_buf, ad_buf, rowptr, srcs, b1, hB, N);

    // ---- Layer 2 ----
    gemm_bf16<<<gWide, 256, 0, stream>>>(hB, Wt2, hA, a_src2, a_dst2, as_buf, ad_buf, N, HC, HC, 4);
    gat_aggregate<4, 4, false><<<waveBlocks, 256, 0, stream>>>(hA, as_buf, ad_buf, rowptr, srcs, b2, hB, N);

    // ---- Layer 3 (H=1) ----
    gemm_bf16<<<gNarrow, 256, 0, stream>>>(hB, Wt3, hC, a_src3, a_dst3, as_buf, ad_buf, N, C, HC, 1);
    gat_aggregate<1, 1, true><<<waveBlocks, 256, 0, stream>>>(hC, as_buf, ad_buf, rowptr, srcs, b3, bufF, N);

    // ---- Pool + classify ----
    hipMemsetAsync(sums, 0, (size_t)(64 * 64 + 64) * 4, stream);
    pool_kernel<<<NPB, 256, 0, stream>>>(bufF, batch, sums, counts, N);
    classify<<<64, 256, 0, stream>>>(sums, counts, Wc, bc, (float*)d_out, NC);
}

// Round 13
// 435.772 us; speedup vs baseline: 1.4718x; 1.0081x over previous
//
#include <hip/hip_runtime.h>

// ---------------------------------------------------------------------------
// GAT 3-layer classifier, bf16 intermediate storage + MFMA GEMMs.
//   CSR build -> per layer: mfma-gemm(+attn epilogue) -> aggregate -> pool/cls
// R6: single-pass softmax (no max-shift), attn fused in GEMM, log2e fold.
// R8/R12: aggregate = one wave/node, predicated U=8 gather rounds (measured
//      optimum: U=4->120us, 8->68.5us, 16->82.5us; split/head-sliced worse).
//      Floor ~68us = 208MB compulsory per-XCD L2 fill + ~73% VALU issue.
// R10: GEMM staging via global_load_lds(16B) + XOR-swizzled LDS (no pad).
// R11: atomic-free scatter; single fused cast kernel.
// R13: full-N GEMM tiles. GEMM1/2: BM=64 x BN=256 (4 waves side-by-side,
//      wave==head) -> A read ONCE (was twice, BN=128<N). GEMM3: BM=256 x
//      BN=64 (waves stacked) -> no wasted columns (was 50% MFMA waste).
// ---------------------------------------------------------------------------

typedef __attribute__((ext_vector_type(8))) __bf16 bf16x8;
typedef __attribute__((ext_vector_type(4))) float f32x4;

#define LOG2E 1.44269504f

static __device__ __forceinline__ unsigned short f2bf(float f) {
    unsigned u = __float_as_uint(f);
    unsigned r = (u + 0x7fffu + ((u >> 16) & 1u)) >> 16;
    return (unsigned short)r;
}
static __device__ __forceinline__ float bf2f(unsigned short s) {
    return __uint_as_float(((unsigned)s) << 16);
}

static __device__ __forceinline__ void g2lds16(const unsigned short* g,
                                               unsigned short* l) {
    __builtin_amdgcn_global_load_lds(
        (const __attribute__((address_space(1))) unsigned int*)g,
        (__attribute__((address_space(3))) unsigned int*)l, 16, 0, 0);
}

// ============================ CSR build ====================================
__global__ void count_edges(const int* __restrict__ ei, int* __restrict__ deg,
                            int* __restrict__ epos, int E) {
    int i = blockIdx.x * blockDim.x + threadIdx.x;
    if (i >= E) return;
    int dst = ei[E + i];
    epos[i] = atomicAdd(&deg[dst], 1);
}

// exclusive scan of (deg[i]+1)  (+1 = self-loop appended at row end)
__global__ __launch_bounds__(256) void scan_partial(const int* __restrict__ deg,
                                                    int* __restrict__ rowptr,
                                                    int* __restrict__ blockSums, int N) {
    int t = threadIdx.x;
    int lane = t & 63, wv = t >> 6;
    int base = blockIdx.x * 1024 + t * 4;
    int v[4];
#pragma unroll
    for (int j = 0; j < 4; ++j) v[j] = (base + j < N) ? deg[base + j] + 1 : 0;
    int local = v[0] + v[1] + v[2] + v[3];
    int x = local;
#pragma unroll
    for (int off = 1; off < 64; off <<= 1) {
        int y = __shfl_up(x, off);
        if (lane >= off) x += y;
    }
    __shared__ int wsum[4];
    if (lane == 63) wsum[wv] = x;
    __syncthreads();
    int woff = 0;
    for (int i = 0; i < wv; ++i) woff += wsum[i];
    int run = woff + x - local;
#pragma unroll
    for (int j = 0; j < 4; ++j) {
        if (base + j < N) rowptr[base + j] = run;
        run += v[j];
    }
    if (t == 255) blockSums[blockIdx.x] = woff + x;
}

__global__ void scan_blocks(int* __restrict__ blockSums, int* __restrict__ rowptr,
                            int NB, int N) {
    int lane = threadIdx.x;  // 64 threads
    int carry = 0;
    for (int b0 = 0; b0 < NB; b0 += 64) {
        int i = b0 + lane;
        int v = (i < NB) ? blockSums[i] : 0;
        int x = v;
#pragma unroll
        for (int off = 1; off < 64; off <<= 1) {
            int y = __shfl_up(x, off);
            if (lane >= off) x += y;
        }
        if (i < NB) blockSums[i] = carry + x - v;
        carry += __shfl(x, 63);
    }
    if (lane == 0) rowptr[N] = carry;
}

__global__ void add_offsets(int* __restrict__ rowptr, const int* __restrict__ blockOffs,
                            int N) {
    int i = blockIdx.x * blockDim.x + threadIdx.x;
    if (i < N) rowptr[i] += blockOffs[i >> 10];
}

// atomic-free scatter: real edge i -> rowptr[dst]+epos[i]; self-loop of d ->
// rowptr[d]+deg[d] (last slot; deg excludes self-loops).
__global__ void scatter_edges(const int* __restrict__ ei, const int* __restrict__ rowptr,
                              const int* __restrict__ deg, const int* __restrict__ epos,
                              int* __restrict__ srcs, int E, int N) {
    int i = blockIdx.x * blockDim.x + threadIdx.x;
    int tot = E + N;
    if (i >= tot) return;
    if (i < E) {
        int dst = ei[E + i];
        srcs[rowptr[dst] + epos[i]] = ei[i];
    } else {
        int d = i - E;
        srcs[rowptr[d] + deg[d]] = d;
    }
}

// ============================ fused casts ==================================
__global__ void prep_cast(const float* __restrict__ x, unsigned short* __restrict__ xb,
                          const float* __restrict__ W1, unsigned short* __restrict__ Wt1,
                          const float* __restrict__ W2, unsigned short* __restrict__ Wt2,
                          const float* __restrict__ W3, unsigned short* __restrict__ Wt3,
                          int n0, int n1, int n2, int n3,
                          int F_IN, int HC, int C) {
    int i = blockIdx.x * blockDim.x + threadIdx.x;
    if (i < n0) {
        float4 v = ((const float4*)x)[i];
        ushort4 o;
        o.x = f2bf(v.x); o.y = f2bf(v.y); o.z = f2bf(v.z); o.w = f2bf(v.w);
        ((ushort4*)xb)[i] = o;
        return;
    }
    i -= n0;
    if (i < n1) {  // Wt1: [HC][F_IN]
        int n = i / F_IN, k = i - n * F_IN;
        Wt1[i] = f2bf(W1[(size_t)k * HC + n]);
        return;
    }
    i -= n1;
    if (i < n2) {  // Wt2: [HC][HC]
        int n = i / HC, k = i - n * HC;
        Wt2[i] = f2bf(W2[(size_t)k * HC + n]);
        return;
    }
    i -= n2;
    if (i < n3) {  // Wt3: [C][HC]
        int n = i / HC, k = i - n * HC;
        Wt3[i] = f2bf(W3[(size_t)k * C + n]);
    }
}

// ============================ MFMA GEMM + attn epilogue ====================
// C[M,BN](bf16) = A[M,K](bf16) @ Bt[BN,K](bf16)^T, BN == N exactly (grid.x=1).
// WAVES_N=4: BM=64, BN=256 (GEMM1/2; wave==head).  WAVES_N=1: BM=256, BN=64
// (GEMM3; waves stacked over rows, head 0).
// Staging via global_load_lds(16B), XOR swizzle seg^=(row>>1)&3; 5 rounds of
// 256 slots, each round matrix-uniform (A-slot count is a multiple of 256).
// as/ad epilogue dots pre-scaled by log2(e).
#define BK 32

template <int WAVES_N>
__global__ __launch_bounds__(256) void gemm_bf16(const unsigned short* __restrict__ A,
                                                 const unsigned short* __restrict__ Bt,
                                                 unsigned short* __restrict__ C,
                                                 const float* __restrict__ a_src,
                                                 const float* __restrict__ a_dst,
                                                 float* __restrict__ as_o,
                                                 float* __restrict__ ad_o,
                                                 int M, int N, int K, int H) {
    constexpr int BMt = (4 / WAVES_N) * 64;
    constexpr int BNt = WAVES_N * 64;
    constexpr int ASLOTS = BMt * 4;               // 16B slots for the A tile
    constexpr int ROUNDS = (BMt + BNt) / 64;      // staging rounds (5)
    __shared__ unsigned short As[BMt * BK];
    __shared__ unsigned short Bs[BNt * BK];
    int t = threadIdx.x;
    int bm = blockIdx.y * BMt;
    int wave = t >> 6, lane = t & 63;
    int wm = (wave / WAVES_N) * 64, wn = (wave % WAVES_N) * 64;
    int quad = lane >> 4, mr = lane & 15;

    f32x4 zero = {0.f, 0.f, 0.f, 0.f};
    f32x4 acc[4][4];
#pragma unroll
    for (int i = 0; i < 4; ++i)
#pragma unroll
        for (int j = 0; j < 4; ++j) acc[i][j] = zero;

    int sw = quad ^ ((mr >> 1) & 3);
    int aoff[4], boff[4];
#pragma unroll
    for (int i = 0; i < 4; ++i) {
        aoff[i] = (wm + i * 16 + mr) * BK + sw * 8;
        boff[i] = (wn + i * 16 + mr) * BK + sw * 8;
    }

    for (int k0 = 0; k0 < K; k0 += BK) {
        __syncthreads();   // prior iteration's reads done before overwrite
#pragma unroll
        for (int r = 0; r < ROUNDS; ++r) {
            int slotw = r * 256 + wave * 64;      // wave-uniform slot base
            int slot = slotw + lane;
            if (slotw < ASLOTS) {
                int row = slot >> 2;
                int sg = (slot & 3) ^ ((row >> 1) & 3);
                int gra = bm + row;
                if (gra < M)
                    g2lds16(&A[(size_t)gra * K + k0 + sg * 8], &As[slotw * 8]);
            } else {
                int bslot = slot - ASLOTS;
                int row = bslot >> 2;
                int sg = (bslot & 3) ^ ((row >> 1) & 3);
                g2lds16(&Bt[(size_t)row * K + k0 + sg * 8], &Bs[(slotw - ASLOTS) * 8]);
            }
        }
        __syncthreads();

        bf16x8 af[4], bfr[4];
#pragma unroll
        for (int i = 0; i < 4; ++i) {
            af[i]  = *(bf16x8*)&As[aoff[i]];
            bfr[i] = *(bf16x8*)&Bs[boff[i]];
        }
#pragma unroll
        for (int i = 0; i < 4; ++i)
#pragma unroll
            for (int j = 0; j < 4; ++j)
                acc[i][j] = __builtin_amdgcn_mfma_f32_16x16x32_bf16(af[i], bfr[j], acc[i][j], 0, 0, 0);
    }

    // attn coefficients: this wave's 64 cols == head wn/64
    {
        int head = wn >> 6;
        float asv[4], adv[4];
#pragma unroll
        for (int j = 0; j < 4; ++j) {
            asv[j] = a_src[head * 64 + j * 16 + mr];
            adv[j] = a_dst[head * 64 + j * 16 + mr];
        }
#pragma unroll
        for (int i = 0; i < 4; ++i) {
#pragma unroll
            for (int r = 0; r < 4; ++r) {
                float ps = acc[i][0][r] * asv[0] + acc[i][1][r] * asv[1]
                         + acc[i][2][r] * asv[2] + acc[i][3][r] * asv[3];
                float pd = acc[i][0][r] * adv[0] + acc[i][1][r] * adv[1]
                         + acc[i][2][r] * adv[2] + acc[i][3][r] * adv[3];
#pragma unroll
                for (int off2 = 1; off2 < 16; off2 <<= 1) {
                    ps += __shfl_xor(ps, off2);
                    pd += __shfl_xor(pd, off2);
                }
                int grow = bm + wm + i * 16 + quad * 4 + r;
                if (mr == 0 && grow < M) {
                    as_o[(size_t)grow * H + head] = ps * LOG2E;
                    ad_o[(size_t)grow * H + head] = pd * LOG2E;
                }
            }
        }
    }

    // C store: C/D layout col=lane&15, row=quad*4+reg
#pragma unroll
    for (int i = 0; i < 4; ++i) {
#pragma unroll
        for (int r = 0; r < 4; ++r) {
            int grow = bm + wm + i * 16 + quad * 4 + r;
            if (grow >= M) continue;
#pragma unroll
            for (int j = 0; j < 4; ++j) {
                int gcol = wn + j * 16 + mr;
                C[(size_t)grow * N + gcol] = f2bf(acc[i][j][r]);
            }
        }
    }
}

// ============================ aggregation ==================================
// Single-pass unnormalized softmax: out = sum(exp(e)*h) / (sum(exp(e))+eps).
// as/ad pre-scaled by log2(e) -> exp2 in the hot loop.
// One wave per node; predicated 8-deep unrolled gather rounds.
template <int H, int VPL, bool OUTF32>
__global__ __launch_bounds__(256) void gat_aggregate(const unsigned short* __restrict__ hbuf,
                                                     const float* __restrict__ as_i,
                                                     const float* __restrict__ ad_i,
                                                     const int* __restrict__ rowptr,
                                                     const int* __restrict__ srcs,
                                                     const float* __restrict__ bias,
                                                     void* __restrict__ out_v, int N) {
    const int HC = 64 * VPL;
    int node = (blockIdx.x * blockDim.x + threadIdx.x) >> 6;
    int lane = threadIdx.x & 63;
    if (node >= N) return;
    int row = rowptr[node], end = rowptr[node + 1];
    int len = end - row;
    const int hd_lane = (lane * VPL) >> 6;

    float advh = ad_i[(size_t)node * H + hd_lane];

    float acc[VPL];
#pragma unroll
    for (int j = 0; j < VPL; ++j) acc[j] = 0.f;
    float l = 0.f;

    const int U = 8;
    for (int base = 0; base < len; base += U) {
        int s[U];
        float cf[U];
#pragma unroll
        for (int u = 0; u < U; ++u) {
            int idx = base + u;
            int ii = row + ((idx < len) ? idx : (len - 1));
            s[u] = srcs[ii];
        }
#pragma unroll
        for (int u = 0; u < U; ++u) cf[u] = as_i[(size_t)s[u] * H + hd_lane];
        if (VPL == 4) {
            ushort4 r[U];
#pragma unroll
            for (int u = 0; u < U; ++u)
                r[u] = *(const ushort4*)&hbuf[(size_t)s[u] * HC + lane * 4];
#pragma unroll
            for (int u = 0; u < U; ++u) {
                float e = cf[u] + advh;
                e = (e > 0.f) ? e : 0.2f * e;
                float wgt = (base + u < len) ? exp2f(e) : 0.f;
                l += wgt;
                acc[0] += wgt * bf2f(r[u].x);
                acc[1] += wgt * bf2f(r[u].y);
                acc[2] += wgt * bf2f(r[u].z);
                acc[3] += wgt * bf2f(r[u].w);
            }
        } else {
            unsigned short r[U];
#pragma unroll
            for (int u = 0; u < U; ++u) r[u] = hbuf[(size_t)s[u] * HC + lane];
#pragma unroll
            for (int u = 0; u < U; ++u) {
                float e = cf[u] + advh;
                e = (e > 0.f) ? e : 0.2f * e;
                float wgt = (base + u < len) ? exp2f(e) : 0.f;
                l += wgt;
                acc[0] += wgt * bf2f(r[u]);
            }
        }
    }

    float inv_l = 1.f / (l + 1e-16f);
    float vals[VPL];
#pragma unroll
    for (int j = 0; j < VPL; ++j) {
        float v = acc[j] * inv_l + bias[lane * VPL + j];
        vals[j] = (v > 0.f) ? v : (__expf(v) - 1.f);
    }
    if (OUTF32) {
        float* out = (float*)out_v;
#pragma unroll
        for (int j = 0; j < VPL; ++j)
            out[(size_t)node * HC + lane * VPL + j] = vals[j];
    } else {
        unsigned short* out = (unsigned short*)out_v;
        if (VPL == 4) {
            ushort4 o;
            o.x = f2bf(vals[0]); o.y = f2bf(vals[1]);
            o.z = f2bf(vals[2]); o.w = f2bf(vals[3]);
            *(ushort4*)&out[(size_t)node * HC + lane * 4] = o;
        } else {
            out[(size_t)node * HC + lane] = f2bf(vals[0]);
        }
    }
}

// ============================ pool + classify ==============================
#define POOL_CHUNK 128
__global__ __launch_bounds__(256) void pool_kernel(const float* __restrict__ hf,
                                                   const int* __restrict__ batch,
                                                   float* __restrict__ sums,
                                                   float* __restrict__ counts, int N) {
    int t = threadIdx.x;
    int c = t & 63, sub = t >> 6;
    int start = blockIdx.x * POOL_CHUNK;
    int end = min(start + POOL_CHUNK, N);
    float acc = 0.f, cnt = 0.f;
    int cur = -1;
    for (int n = start + sub; n < end; n += 4) {
        int g = batch[n];
        if (g != cur) {
            if (cur >= 0) {
                atomicAdd(&sums[cur * 64 + c], acc);
                if (c == 0) atomicAdd(&counts[cur], cnt);
            }
            cur = g; acc = 0.f; cnt = 0.f;
        }
        acc += hf[(size_t)n * 64 + c];
        cnt += 1.f;
    }
    if (cur >= 0) {
        atomicAdd(&sums[cur * 64 + c], acc);
        if (c == 0) atomicAdd(&counts[cur], cnt);
    }
}

__global__ void classify(const float* __restrict__ sums, const float* __restrict__ counts,
                         const float* __restrict__ Wc, const float* __restrict__ bc,
                         float* __restrict__ out, int NC) {
    __shared__ float p[64];
    int g = blockIdx.x;
    if (threadIdx.x < 64) {
        float cnt = fmaxf(counts[g], 1.0f);
        p[threadIdx.x] = sums[g * 64 + threadIdx.x] / cnt;
    }
    __syncthreads();
    int k = threadIdx.x;
    if (k < NC) {
        float acc = bc[k];
        for (int c = 0; c < 64; ++c) acc += p[c] * Wc[c * NC + k];
        out[g * NC + k] = acc;
    }
}

static inline size_t align_up(size_t x, size_t a) { return (x + a - 1) / a * a; }

extern "C" void kernel_launch(void* const* d_in, const int* in_sizes, int n_in,
                              void* d_out, int out_size, void* d_ws, size_t ws_size,
                              hipStream_t stream) {
    const float* x      = (const float*)d_in[0];
    const int*   ei     = (const int*)d_in[1];
    const int*   batch  = (const int*)d_in[2];
    const float* W1     = (const float*)d_in[3];
    const float* a_src1 = (const float*)d_in[4];
    const float* a_dst1 = (const float*)d_in[5];
    const float* b1     = (const float*)d_in[6];
    const float* W2     = (const float*)d_in[7];
    const float* a_src2 = (const float*)d_in[8];
    const float* a_dst2 = (const float*)d_in[9];
    const float* b2     = (const float*)d_in[10];
    const float* W3     = (const float*)d_in[11];
    const float* a_src3 = (const float*)d_in[12];
    const float* a_dst3 = (const float*)d_in[13];
    const float* b3     = (const float*)d_in[14];
    const float* Wc     = (const float*)d_in[15];
    const float* bc     = (const float*)d_in[16];

    const int N    = in_sizes[2];
    const int E    = in_sizes[1] / 2;
    const int F_IN = in_sizes[0] / N;   // 128
    const int HC   = in_sizes[6];       // 256
    const int C    = in_sizes[14];      // 64
    const int NC   = in_sizes[16];      // 200
    const int Etot = E + N;
    const int NB   = (N + 1023) / 1024;
    const int NPB  = (N + POOL_CHUNK - 1) / POOL_CHUNK;

    char* w = (char*)d_ws;
    size_t off = 0;
    auto alloc = [&](size_t bytes) -> void* {
        void* p = w + off;
        off = align_up(off + bytes, 256);
        return p;
    };
    int*   deg    = (int*)alloc((size_t)N * 4);
    int*   rowptr = (int*)alloc((size_t)(N + 1) * 4);
    int*   epos   = (int*)alloc((size_t)E * 4);
    int*   srcs   = (int*)alloc((size_t)Etot * 4);
    int*   bsums  = (int*)alloc((size_t)NB * 4);
    float* as_buf = (float*)alloc((size_t)N * 4 * 4);
    float* ad_buf = (float*)alloc((size_t)N * 4 * 4);
    unsigned short* xb  = (unsigned short*)alloc((size_t)N * F_IN * 2);
    unsigned short* Wt1 = (unsigned short*)alloc((size_t)HC * F_IN * 2);
    unsigned short* Wt2 = (unsigned short*)alloc((size_t)HC * HC * 2);
    unsigned short* Wt3 = (unsigned short*)alloc((size_t)C * HC * 2);
    unsigned short* hA  = (unsigned short*)alloc((size_t)N * HC * 2);
    unsigned short* hB  = (unsigned short*)alloc((size_t)N * HC * 2);
    unsigned short* hC  = (unsigned short*)alloc((size_t)N * C * 2);
    float* bufF   = (float*)alloc((size_t)N * C * 4);
    float* sums   = (float*)alloc((size_t)(64 * 64 + 64) * 4);
    float* counts = sums + 64 * 64;

    const int TPB = 256;

    // ---- CSR build (atomic-free scatter) ----
    hipMemsetAsync(deg, 0, (size_t)N * 4, stream);
    count_edges<<<(E + TPB - 1) / TPB, TPB, 0, stream>>>(ei, deg, epos, E);
    scan_partial<<<NB, 256, 0, stream>>>(deg, rowptr, bsums, N);
    scan_blocks<<<1, 64, 0, stream>>>(bsums, rowptr, NB, N);
    add_offsets<<<(N + TPB - 1) / TPB, TPB, 0, stream>>>(rowptr, bsums, N);
    scatter_edges<<<(Etot + TPB - 1) / TPB, TPB, 0, stream>>>(ei, rowptr, deg, epos, srcs, E, N);

    // ---- fused casts (1 launch) ----
    int n0 = N * F_IN / 4, n1 = HC * F_IN, n2 = HC * HC, n3 = C * HC;
    int ntot = n0 + n1 + n2 + n3;
    prep_cast<<<(ntot + TPB - 1) / TPB, TPB, 0, stream>>>(
        x, xb, W1, Wt1, W2, Wt2, W3, Wt3, n0, n1, n2, n3, F_IN, HC, C);

    dim3 gWide(1, (N + 63) / 64);        // BM=64 x BN=256
    dim3 gNarrow(1, (N + 255) / 256);    // BM=256 x BN=64
    int waveBlocks = (N + 3) / 4;

    // ---- Layer 1 ----
    gemm_bf16<4><<<gWide, 256, 0, stream>>>(xb, Wt1, hA, a_src1, a_dst1, as_buf, ad_buf, N, HC, F_IN, 4);
    gat_aggregate<4, 4, false><<<waveBlocks, 256, 0, stream>>>(hA, as_buf, ad_buf, rowptr, srcs, b1, hB, N);

    // ---- Layer 2 ----
    gemm_bf16<4><<<gWide, 256, 0, stream>>>(hB, Wt2, hA, a_src2, a_dst2, as_buf, ad_buf, N, HC, HC, 4);
    gat_aggregate<4, 4, false><<<waveBlocks, 256, 0, stream>>>(hA, as_buf, ad_buf, rowptr, srcs, b2, hB, N);

    // ---- Layer 3 (H=1) ----
    gemm_bf16<1><<<gNarrow, 256, 0, stream>>>(hB, Wt3, hC, a_src3, a_dst3, as_buf, ad_buf, N, C, HC, 1);
    gat_aggregate<1, 1, true><<<waveBlocks, 256, 0, stream>>>(hC, as_buf, ad_buf, rowptr, srcs, b3, bufF, N);

    // ---- Pool + classify ----
    hipMemsetAsync(sums, 0, (size_t)(64 * 64 + 64) * 4, stream);
    pool_kernel<<<NPB, 256, 0, stream>>>(bufF, batch, sums, counts, N);
    classify<<<64, 256, 0, stream>>>(sums, counts, Wc, bc, (float*)d_out, NC);
}

// Round 14
// 424.982 us; speedup vs baseline: 1.5092x; 1.0254x over previous
//
#include <hip/hip_runtime.h>

// ---------------------------------------------------------------------------
// GAT 3-layer classifier, bf16 intermediate storage + MFMA GEMMs.
//   CSR build -> per layer: mfma-gemm(+attn epilogue) -> aggregate -> pool/cls
// R6: single-pass softmax (no max-shift), attn fused in GEMM, log2e fold.
// R8/R12: aggregate = one wave/node, predicated U=8 gather rounds (measured
//      optimum). Floor ~68us = 208MB compulsory per-XCD L2 fill + ~73% VALU.
// R10: GEMM staging via global_load_lds(16B) + XOR-swizzled LDS (no pad).
// R11: atomic-free scatter; fused cast kernel.  R13: full-N GEMM tiles.
// R14: GEMM1 stages A from f32 x directly (xb buffer deleted); add_offsets
//      folded into scatter/aggregates via bsums chunk offsets; single fused
//      memset (deg+sums adjacent); leaky_relu as fmax(e, 0.2e).
// ---------------------------------------------------------------------------

typedef __attribute__((ext_vector_type(8))) __bf16 bf16x8;
typedef __attribute__((ext_vector_type(4))) float f32x4;

#define LOG2E 1.44269504f

static __device__ __forceinline__ unsigned short f2bf(float f) {
    unsigned u = __float_as_uint(f);
    unsigned r = (u + 0x7fffu + ((u >> 16) & 1u)) >> 16;
    return (unsigned short)r;
}
static __device__ __forceinline__ float bf2f(unsigned short s) {
    return __uint_as_float(((unsigned)s) << 16);
}

static __device__ __forceinline__ void g2lds16(const unsigned short* g,
                                               unsigned short* l) {
    __builtin_amdgcn_global_load_lds(
        (const __attribute__((address_space(1))) unsigned int*)g,
        (__attribute__((address_space(3))) unsigned int*)l, 16, 0, 0);
}

// ============================ CSR build ====================================
__global__ void count_edges(const int* __restrict__ ei, int* __restrict__ deg,
                            int* __restrict__ epos, int E) {
    int i = blockIdx.x * blockDim.x + threadIdx.x;
    if (i >= E) return;
    int dst = ei[E + i];
    epos[i] = atomicAdd(&deg[dst], 1);
}

// exclusive scan of (deg[i]+1), per-1024 chunk (chunk offsets in blockSums)
__global__ __launch_bounds__(256) void scan_partial(const int* __restrict__ deg,
                                                    int* __restrict__ rowptr,
                                                    int* __restrict__ blockSums, int N) {
    int t = threadIdx.x;
    int lane = t & 63, wv = t >> 6;
    int base = blockIdx.x * 1024 + t * 4;
    int v[4];
#pragma unroll
    for (int j = 0; j < 4; ++j) v[j] = (base + j < N) ? deg[base + j] + 1 : 0;
    int local = v[0] + v[1] + v[2] + v[3];
    int x = local;
#pragma unroll
    for (int off = 1; off < 64; off <<= 1) {
        int y = __shfl_up(x, off);
        if (lane >= off) x += y;
    }
    __shared__ int wsum[4];
    if (lane == 63) wsum[wv] = x;
    __syncthreads();
    int woff = 0;
    for (int i = 0; i < wv; ++i) woff += wsum[i];
    int run = woff + x - local;
#pragma unroll
    for (int j = 0; j < 4; ++j) {
        if (base + j < N) rowptr[base + j] = run;
        run += v[j];
    }
    if (t == 255) blockSums[blockIdx.x] = woff + x;
}

// scan chunk totals in place (exclusive). rowptr[N] is written such that
// rowptr[N] + blockSums[N>>10] == total, so consumers can uniformly add the
// chunk offset for any index 0..N.  blockSums has NB+1 slots.
__global__ void scan_blocks(int* __restrict__ blockSums, int* __restrict__ rowptr,
                            int NB, int N) {
    int lane = threadIdx.x;  // 64 threads
    int carry = 0;
    for (int b0 = 0; b0 < NB; b0 += 64) {
        int i = b0 + lane;
        int v = (i < NB) ? blockSums[i] : 0;
        int x = v;
#pragma unroll
        for (int off = 1; off < 64; off <<= 1) {
            int y = __shfl_up(x, off);
            if (lane >= off) x += y;
        }
        if (i < NB) blockSums[i] = carry + x - v;
        carry += __shfl(x, 63);
    }
    if (lane == 0) {
        int c = N >> 10;
        int offN;
        if (c < NB) {
            offN = blockSums[c];
        } else {
            blockSums[c] = 0;   // slot NB exists (alloc NB+1)
            offN = 0;
        }
        rowptr[N] = carry - offN;
    }
}

// atomic-free scatter with inline chunk offset.
__global__ void scatter_edges(const int* __restrict__ ei, const int* __restrict__ rowptr,
                              const int* __restrict__ bs,
                              const int* __restrict__ deg, const int* __restrict__ epos,
                              int* __restrict__ srcs, int E, int N) {
    int i = blockIdx.x * blockDim.x + threadIdx.x;
    int tot = E + N;
    if (i >= tot) return;
    if (i < E) {
        int dst = ei[E + i];
        srcs[rowptr[dst] + bs[dst >> 10] + epos[i]] = ei[i];
    } else {
        int d = i - E;
        srcs[rowptr[d] + bs[d >> 10] + deg[d]] = d;
    }
}

// ============================ fused weight casts ===========================
__global__ void prep_cast(const float* __restrict__ W1, unsigned short* __restrict__ Wt1,
                          const float* __restrict__ W2, unsigned short* __restrict__ Wt2,
                          const float* __restrict__ W3, unsigned short* __restrict__ Wt3,
                          int n1, int n2, int n3, int F_IN, int HC, int C) {
    int i = blockIdx.x * blockDim.x + threadIdx.x;
    if (i < n1) {  // Wt1: [HC][F_IN]
        int n = i / F_IN, k = i - n * F_IN;
        Wt1[i] = f2bf(W1[(size_t)k * HC + n]);
        return;
    }
    i -= n1;
    if (i < n2) {  // Wt2: [HC][HC]
        int n = i / HC, k = i - n * HC;
        Wt2[i] = f2bf(W2[(size_t)k * HC + n]);
        return;
    }
    i -= n2;
    if (i < n3) {  // Wt3: [C][HC]
        int n = i / HC, k = i - n * HC;
        Wt3[i] = f2bf(W3[(size_t)k * C + n]);
    }
}

// ============================ MFMA GEMM + attn epilogue ====================
// C[M,BN](bf16) = A[M,K] @ Bt[BN,K](bf16)^T, BN == N exactly (grid.x=1).
// WAVES_N=4: BM=64, BN=256 (wave==head).  WAVES_N=1: BM=256, BN=64.
// AF32 (WAVES_N=4 only): A is f32, converted in VGPR staging (fuses the x
// cast); B via global_load_lds.  Otherwise both matrices via global_load_lds
// (16B) with XOR swizzle seg^=(row>>1)&3 (fragment ds_read_b128 2-way = free).
// as/ad epilogue dots pre-scaled by log2(e).
#define BK 32

template <bool AF32, int WAVES_N>
__global__ __launch_bounds__(256) void gemm_bf16(const void* __restrict__ Av,
                                                 const unsigned short* __restrict__ Bt,
                                                 unsigned short* __restrict__ C,
                                                 const float* __restrict__ a_src,
                                                 const float* __restrict__ a_dst,
                                                 float* __restrict__ as_o,
                                                 float* __restrict__ ad_o,
                                                 int M, int N, int K, int H) {
    constexpr int BMt = (4 / WAVES_N) * 64;
    constexpr int BNt = WAVES_N * 64;
    constexpr int ASLOTS = BMt * 4;               // 16B slots for the A tile
    constexpr int ROUNDS = (BMt + BNt) / 64;      // g2lds rounds (non-AF32)
    __shared__ unsigned short As[BMt * BK];
    __shared__ unsigned short Bs[BNt * BK];
    int t = threadIdx.x;
    int bm = blockIdx.y * BMt;
    int wave = t >> 6, lane = t & 63;
    int wm = (wave / WAVES_N) * 64, wn = (wave % WAVES_N) * 64;
    int quad = lane >> 4, mr = lane & 15;

    f32x4 zero = {0.f, 0.f, 0.f, 0.f};
    f32x4 acc[4][4];
#pragma unroll
    for (int i = 0; i < 4; ++i)
#pragma unroll
        for (int j = 0; j < 4; ++j) acc[i][j] = zero;

    int sw = quad ^ ((mr >> 1) & 3);
    int aoff[4], boff[4];
#pragma unroll
    for (int i = 0; i < 4; ++i) {
        aoff[i] = (wm + i * 16 + mr) * BK + sw * 8;
        boff[i] = (wn + i * 16 + mr) * BK + sw * 8;
    }

    for (int k0 = 0; k0 < K; k0 += BK) {
        ushort4 ua0, ua1;
        if (AF32) {
            // ASLOTS == 256 == blockDim for WAVES_N=4: one A slot per thread
            int slot = t;
            int row = slot >> 2;
            int sg = (slot & 3) ^ ((row >> 1) & 3);
            int gra = bm + row;
            float4 lo = make_float4(0.f, 0.f, 0.f, 0.f), hi = lo;
            if (gra < M) {
                const float* Af = (const float*)Av;
                lo = *(const float4*)&Af[(size_t)gra * K + k0 + sg * 8];
                hi = *(const float4*)&Af[(size_t)gra * K + k0 + sg * 8 + 4];
            }
            ua0 = make_ushort4(f2bf(lo.x), f2bf(lo.y), f2bf(lo.z), f2bf(lo.w));
            ua1 = make_ushort4(f2bf(hi.x), f2bf(hi.y), f2bf(hi.z), f2bf(hi.w));
        }
        __syncthreads();   // prior iteration's reads done before overwrite
        if (AF32) {
            int slot = t;
            *(ushort4*)&As[slot * 8]     = ua0;
            *(ushort4*)&As[slot * 8 + 4] = ua1;
#pragma unroll
            for (int r = 0; r < BNt / 64; ++r) {
                int slotw = r * 256 + wave * 64;
                int bslot = slotw + lane;
                int row = bslot >> 2;
                int sg = (bslot & 3) ^ ((row >> 1) & 3);
                g2lds16(&Bt[(size_t)row * K + k0 + sg * 8], &Bs[slotw * 8]);
            }
        } else {
            const unsigned short* Ab = (const unsigned short*)Av;
#pragma unroll
            for (int r = 0; r < ROUNDS; ++r) {
                int slotw = r * 256 + wave * 64;      // wave-uniform slot base
                int slot = slotw + lane;
                if (slotw < ASLOTS) {
                    int row = slot >> 2;
                    int sg = (slot & 3) ^ ((row >> 1) & 3);
                    int gra = bm + row;
                    if (gra < M)
                        g2lds16(&Ab[(size_t)gra * K + k0 + sg * 8], &As[slotw * 8]);
                } else {
                    int bslot = slot - ASLOTS;
                    int row = bslot >> 2;
                    int sg = (bslot & 3) ^ ((row >> 1) & 3);
                    g2lds16(&Bt[(size_t)row * K + k0 + sg * 8], &Bs[(slotw - ASLOTS) * 8]);
                }
            }
        }
        __syncthreads();

        bf16x8 af[4], bfr[4];
#pragma unroll
        for (int i = 0; i < 4; ++i) {
            af[i]  = *(bf16x8*)&As[aoff[i]];
            bfr[i] = *(bf16x8*)&Bs[boff[i]];
        }
#pragma unroll
        for (int i = 0; i < 4; ++i)
#pragma unroll
            for (int j = 0; j < 4; ++j)
                acc[i][j] = __builtin_amdgcn_mfma_f32_16x16x32_bf16(af[i], bfr[j], acc[i][j], 0, 0, 0);
    }

    // attn coefficients: this wave's 64 cols == head wn/64
    {
        int head = wn >> 6;
        float asv[4], adv[4];
#pragma unroll
        for (int j = 0; j < 4; ++j) {
            asv[j] = a_src[head * 64 + j * 16 + mr];
            adv[j] = a_dst[head * 64 + j * 16 + mr];
        }
#pragma unroll
        for (int i = 0; i < 4; ++i) {
#pragma unroll
            for (int r = 0; r < 4; ++r) {
                float ps = acc[i][0][r] * asv[0] + acc[i][1][r] * asv[1]
                         + acc[i][2][r] * asv[2] + acc[i][3][r] * asv[3];
                float pd = acc[i][0][r] * adv[0] + acc[i][1][r] * adv[1]
                         + acc[i][2][r] * adv[2] + acc[i][3][r] * adv[3];
#pragma unroll
                for (int off2 = 1; off2 < 16; off2 <<= 1) {
                    ps += __shfl_xor(ps, off2);
                    pd += __shfl_xor(pd, off2);
                }
                int grow = bm + wm + i * 16 + quad * 4 + r;
                if (mr == 0 && grow < M) {
                    as_o[(size_t)grow * H + head] = ps * LOG2E;
                    ad_o[(size_t)grow * H + head] = pd * LOG2E;
                }
            }
        }
    }

    // C store: C/D layout col=lane&15, row=quad*4+reg
#pragma unroll
    for (int i = 0; i < 4; ++i) {
#pragma unroll
        for (int r = 0; r < 4; ++r) {
            int grow = bm + wm + i * 16 + quad * 4 + r;
            if (grow >= M) continue;
#pragma unroll
            for (int j = 0; j < 4; ++j) {
                int gcol = wn + j * 16 + mr;
                C[(size_t)grow * N + gcol] = f2bf(acc[i][j][r]);
            }
        }
    }
}

// ============================ aggregation ==================================
// Single-pass unnormalized softmax: out = sum(exp(e)*h) / (sum(exp(e))+eps).
// as/ad pre-scaled by log2(e) -> exp2 in the hot loop; leaky = fmax(e, 0.2e).
// One wave per node; predicated 8-deep unrolled gather rounds.
// rowptr is per-chunk; bs[] supplies the chunk offset inline.
template <int H, int VPL, bool OUTF32>
__global__ __launch_bounds__(256) void gat_aggregate(const unsigned short* __restrict__ hbuf,
                                                     const float* __restrict__ as_i,
                                                     const float* __restrict__ ad_i,
                                                     const int* __restrict__ rowptr,
                                                     const int* __restrict__ bs,
                                                     const int* __restrict__ srcs,
                                                     const float* __restrict__ bias,
                                                     void* __restrict__ out_v, int N) {
    const int HC = 64 * VPL;
    int node = (blockIdx.x * blockDim.x + threadIdx.x) >> 6;
    int lane = threadIdx.x & 63;
    if (node >= N) return;
    int row = rowptr[node] + bs[node >> 10];
    int end = rowptr[node + 1] + bs[(node + 1) >> 10];
    int len = end - row;
    const int hd_lane = (lane * VPL) >> 6;

    float advh = ad_i[(size_t)node * H + hd_lane];

    float acc[VPL];
#pragma unroll
    for (int j = 0; j < VPL; ++j) acc[j] = 0.f;
    float l = 0.f;

    const int U = 8;
    for (int base = 0; base < len; base += U) {
        int s[U];
        float cf[U];
#pragma unroll
        for (int u = 0; u < U; ++u) {
            int idx = base + u;
            int ii = row + ((idx < len) ? idx : (len - 1));
            s[u] = srcs[ii];
        }
#pragma unroll
        for (int u = 0; u < U; ++u) cf[u] = as_i[(size_t)s[u] * H + hd_lane];
        if (VPL == 4) {
            ushort4 r[U];
#pragma unroll
            for (int u = 0; u < U; ++u)
                r[u] = *(const ushort4*)&hbuf[(size_t)s[u] * HC + lane * 4];
#pragma unroll
            for (int u = 0; u < U; ++u) {
                float e = cf[u] + advh;
                e = fmaxf(e, 0.2f * e);
                float wgt = (base + u < len) ? exp2f(e) : 0.f;
                l += wgt;
                acc[0] += wgt * bf2f(r[u].x);
                acc[1] += wgt * bf2f(r[u].y);
                acc[2] += wgt * bf2f(r[u].z);
                acc[3] += wgt * bf2f(r[u].w);
            }
        } else {
            unsigned short r[U];
#pragma unroll
            for (int u = 0; u < U; ++u) r[u] = hbuf[(size_t)s[u] * HC + lane];
#pragma unroll
            for (int u = 0; u < U; ++u) {
                float e = cf[u] + advh;
                e = fmaxf(e, 0.2f * e);
                float wgt = (base + u < len) ? exp2f(e) : 0.f;
                l += wgt;
                acc[0] += wgt * bf2f(r[u]);
            }
        }
    }

    float inv_l = 1.f / (l + 1e-16f);
    float vals[VPL];
#pragma unroll
    for (int j = 0; j < VPL; ++j) {
        float v = acc[j] * inv_l + bias[lane * VPL + j];
        vals[j] = (v > 0.f) ? v : (__expf(v) - 1.f);
    }
    if (OUTF32) {
        float* out = (float*)out_v;
#pragma unroll
        for (int j = 0; j < VPL; ++j)
            out[(size_t)node * HC + lane * VPL + j] = vals[j];
    } else {
        unsigned short* out = (unsigned short*)out_v;
        if (VPL == 4) {
            ushort4 o;
            o.x = f2bf(vals[0]); o.y = f2bf(vals[1]);
            o.z = f2bf(vals[2]); o.w = f2bf(vals[3]);
            *(ushort4*)&out[(size_t)node * HC + lane * 4] = o;
        } else {
            out[(size_t)node * HC + lane] = f2bf(vals[0]);
        }
    }
}

// ============================ pool + classify ==============================
#define POOL_CHUNK 128
__global__ __launch_bounds__(256) void pool_kernel(const float* __restrict__ hf,
                                                   const int* __restrict__ batch,
                                                   float* __restrict__ sums,
                                                   float* __restrict__ counts, int N) {
    int t = threadIdx.x;
    int c = t & 63, sub = t >> 6;
    int start = blockIdx.x * POOL_CHUNK;
    int end = min(start + POOL_CHUNK, N);
    float acc = 0.f, cnt = 0.f;
    int cur = -1;
    for (int n = start + sub; n < end; n += 4) {
        int g = batch[n];
        if (g != cur) {
            if (cur >= 0) {
                atomicAdd(&sums[cur * 64 + c], acc);
                if (c == 0) atomicAdd(&counts[cur], cnt);
            }
            cur = g; acc = 0.f; cnt = 0.f;
        }
        acc += hf[(size_t)n * 64 + c];
        cnt += 1.f;
    }
    if (cur >= 0) {
        atomicAdd(&sums[cur * 64 + c], acc);
        if (c == 0) atomicAdd(&counts[cur], cnt);
    }
}

__global__ void classify(const float* __restrict__ sums, const float* __restrict__ counts,
                         const float* __restrict__ Wc, const float* __restrict__ bc,
                         float* __restrict__ out, int NC) {
    __shared__ float p[64];
    int g = blockIdx.x;
    if (threadIdx.x < 64) {
        float cnt = fmaxf(counts[g], 1.0f);
        p[threadIdx.x] = sums[g * 64 + threadIdx.x] / cnt;
    }
    __syncthreads();
    int k = threadIdx.x;
    if (k < NC) {
        float acc = bc[k];
        for (int c = 0; c < 64; ++c) acc += p[c] * Wc[c * NC + k];
        out[g * NC + k] = acc;
    }
}

static inline size_t align_up(size_t x, size_t a) { return (x + a - 1) / a * a; }

extern "C" void kernel_launch(void* const* d_in, const int* in_sizes, int n_in,
                              void* d_out, int out_size, void* d_ws, size_t ws_size,
                              hipStream_t stream) {
    const float* x      = (const float*)d_in[0];
    const int*   ei     = (const int*)d_in[1];
    const int*   batch  = (const int*)d_in[2];
    const float* W1     = (const float*)d_in[3];
    const float* a_src1 = (const float*)d_in[4];
    const float* a_dst1 = (const float*)d_in[5];
    const float* b1     = (const float*)d_in[6];
    const float* W2     = (const float*)d_in[7];
    const float* a_src2 = (const float*)d_in[8];
    const float* a_dst2 = (const float*)d_in[9];
    const float* b2     = (const float*)d_in[10];
    const float* W3     = (const float*)d_in[11];
    const float* a_src3 = (const float*)d_in[12];
    const float* a_dst3 = (const float*)d_in[13];
    const float* b3     = (const float*)d_in[14];
    const float* Wc     = (const float*)d_in[15];
    const float* bc     = (const float*)d_in[16];

    const int N    = in_sizes[2];
    const int E    = in_sizes[1] / 2;
    const int F_IN = in_sizes[0] / N;   // 128
    const int HC   = in_sizes[6];       // 256
    const int C    = in_sizes[14];      // 64
    const int NC   = in_sizes[16];      // 200
    const int Etot = E + N;
    const int NB   = (N + 1023) / 1024;
    const int NPB  = (N + POOL_CHUNK - 1) / POOL_CHUNK;

    char* w = (char*)d_ws;
    size_t off = 0;
    auto alloc = [&](size_t bytes) -> void* {
        void* p = w + off;
        off = align_up(off + bytes, 256);
        return p;
    };
    // deg and sums adjacent -> one memset zeroes both
    int*   deg    = (int*)alloc((size_t)N * 4);
    float* sums   = (float*)alloc((size_t)(64 * 64 + 64) * 4);
    float* counts = sums + 64 * 64;
    int*   rowptr = (int*)alloc((size_t)(N + 1) * 4);
    int*   epos   = (int*)alloc((size_t)E * 4);
    int*   srcs   = (int*)alloc((size_t)Etot * 4);
    int*   bsums  = (int*)alloc((size_t)(NB + 1) * 4);
    float* as_buf = (float*)alloc((size_t)N * 4 * 4);
    float* ad_buf = (float*)alloc((size_t)N * 4 * 4);
    unsigned short* Wt1 = (unsigned short*)alloc((size_t)HC * F_IN * 2);
    unsigned short* Wt2 = (unsigned short*)alloc((size_t)HC * HC * 2);
    unsigned short* Wt3 = (unsigned short*)alloc((size_t)C * HC * 2);
    unsigned short* hA  = (unsigned short*)alloc((size_t)N * HC * 2);
    unsigned short* hB  = (unsigned short*)alloc((size_t)N * HC * 2);
    unsigned short* hC  = (unsigned short*)alloc((size_t)N * C * 2);
    float* bufF   = (float*)alloc((size_t)N * C * 4);

    const int TPB = 256;

    // ---- zero deg + sums in one shot ----
    hipMemsetAsync(deg, 0, (char*)(sums + 64 * 64 + 64) - (char*)deg, stream);

    // ---- CSR build (atomic-free scatter, chunk offsets applied inline) ----
    count_edges<<<(E + TPB - 1) / TPB, TPB, 0, stream>>>(ei, deg, epos, E);
    scan_partial<<<NB, 256, 0, stream>>>(deg, rowptr, bsums, N);
    scan_blocks<<<1, 64, 0, stream>>>(bsums, rowptr, NB, N);
    scatter_edges<<<(Etot + TPB - 1) / TPB, TPB, 0, stream>>>(ei, rowptr, bsums, deg, epos, srcs, E, N);

    // ---- fused weight casts (1 launch; x handled inside GEMM1) ----
    int n1 = HC * F_IN, n2 = HC * HC, n3 = C * HC;
    int ntot = n1 + n2 + n3;
    prep_cast<<<(ntot + TPB - 1) / TPB, TPB, 0, stream>>>(
        W1, Wt1, W2, Wt2, W3, Wt3, n1, n2, n3, F_IN, HC, C);

    dim3 gWide(1, (N + 63) / 64);        // BM=64 x BN=256
    dim3 gNarrow(1, (N + 255) / 256);    // BM=256 x BN=64
    int waveBlocks = (N + 3) / 4;

    // ---- Layer 1 (A = f32 x, converted in staging) ----
    gemm_bf16<true, 4><<<gWide, 256, 0, stream>>>(x, Wt1, hA, a_src1, a_dst1, as_buf, ad_buf, N, HC, F_IN, 4);
    gat_aggregate<4, 4, false><<<waveBlocks, 256, 0, stream>>>(hA, as_buf, ad_buf, rowptr, bsums, srcs, b1, hB, N);

    // ---- Layer 2 ----
    gemm_bf16<false, 4><<<gWide, 256, 0, stream>>>(hB, Wt2, hA, a_src2, a_dst2, as_buf, ad_buf, N, HC, HC, 4);
    gat_aggregate<4, 4, false><<<waveBlocks, 256, 0, stream>>>(hA, as_buf, ad_buf, rowptr, bsums, srcs, b2, hB, N);

    // ---- Layer 3 (H=1) ----
    gemm_bf16<false, 1><<<gNarrow, 256, 0, stream>>>(hB, Wt3, hC, a_src3, a_dst3, as_buf, ad_buf, N, C, HC, 1);
    gat_aggregate<1, 1, true><<<waveBlocks, 256, 0, stream>>>(hC, as_buf, ad_buf, rowptr, bsums, srcs, b3, bufF, N);

    // ---- Pool + classify ----
    pool_kernel<<<NPB, 256, 0, stream>>>(bufF, batch, sums, counts, N);
    classify<<<64, 256, 0, stream>>>(sums, counts, Wc, bc, (float*)d_out, NC);
}